// Round 9
// baseline (208.332 us; speedup 1.0000x reference)
//
#include <hip/hip_runtime.h>
#include <math.h>

#define N0 4096
#define FDIM 500
#define H 256
#define KP1 3072
#define KP2 2304
#define KP3 1728
#define CAP 131072u
#define KPAD 512

typedef __attribute__((ext_vector_type(8))) short bf16x8;
typedef __attribute__((ext_vector_type(4))) float f32x4;
typedef unsigned short ush;

__device__ inline ush f2bf(float x) {
  unsigned u = __float_as_uint(x);
  unsigned r = (u + 0x7fffu + ((u >> 16) & 1u)) >> 16;
  return (ush)r;
}
__device__ inline float bf2f(ush h) { return __uint_as_float(((unsigned)h) << 16); }
__device__ inline unsigned fsort(float f) {
  unsigned u = __float_as_uint(f);
  return (u & 0x80000000u) ? ~u : (u | 0x80000000u);
}
__device__ inline float funsort(unsigned s) {
  return __uint_as_float((s & 0x80000000u) ? (s & 0x7fffffffu) : ~s);
}

// ---------------- fused preamble: convsq (2 rows/block, float4) | Wt conv | init ----------------
__global__ void pre_kernel(const float* __restrict__ X,
                           const float* __restrict__ W1, const float* __restrict__ W2,
                           const float* __restrict__ W3,
                           ush* __restrict__ Xh, ush* __restrict__ Xm, float* __restrict__ sq,
                           ush* Wth1, ush* Wtm1, ush* Wth2, ush* Wtm2, ush* Wth3, ush* Wtm3,
                           unsigned* dmax, unsigned* ecnt, float* deg,
                           unsigned* cmax, float* csum) {
  int blk = blockIdx.x, t = threadIdx.x;
  if (blk < 2048) {
    int half = t >> 7, tt = t & 127;
    int row = blk * 2 + half;
    float s = 0.f;
    if (tt < 125) {
      float4 x4 = ((const float4*)(X + (size_t)row * FDIM))[tt];
      int kx = tt * 4;
      float xs[4] = {x4.x, x4.y, x4.z, x4.w};
      ushort4 hh, mm;
      ush h;
      h = f2bf(xs[0]); hh.x = h; mm.x = f2bf(xs[0] - bf2f(h));
      h = f2bf(xs[1]); hh.y = h; mm.y = f2bf(xs[1] - bf2f(h));
      h = f2bf(xs[2]); hh.z = h; mm.z = f2bf(xs[2] - bf2f(h));
      h = f2bf(xs[3]); hh.w = h; mm.w = f2bf(xs[3] - bf2f(h));
      *(ushort4*)&Xh[(size_t)row * KPAD + kx] = hh;
      *(ushort4*)&Xm[(size_t)row * KPAD + kx] = mm;
      s = xs[0]*xs[0] + xs[1]*xs[1] + xs[2]*xs[2] + xs[3]*xs[3];
    } else {
      int kx = 500 + (tt - 125) * 4;
      ushort4 z = {0, 0, 0, 0};
      *(ushort4*)&Xh[(size_t)row * KPAD + kx] = z;
      *(ushort4*)&Xm[(size_t)row * KPAD + kx] = z;
    }
    for (int off = 32; off; off >>= 1) s += __shfl_down(s, off);
    __shared__ float sw[4];
    if ((t & 63) == 0) sw[t >> 6] = s;
    __syncthreads();
    if ((t & 127) == 0) sq[row] = sw[half * 2] + sw[half * 2 + 1];
  } else if (blk < 3072) {
    int b = blk - 2048;
    const float* W; ush *Ph, *Pm; int K, KP, k;
    if (b < 512)      { W = W1; Ph = Wth1; Pm = Wtm1; K = FDIM; KP = 512; k = b; }
    else if (b < 768) { W = W2; Ph = Wth2; Pm = Wtm2; K = 256;  KP = 256; k = b - 512; }
    else              { W = W3; Ph = Wth3; Pm = Wtm3; K = 256;  KP = 256; k = b - 768; }
    float x = (k < K) ? W[(size_t)k * 256 + t] : 0.f;
    ush h = f2bf(x);
    Ph[(size_t)t * KP + k] = h;
    Pm[(size_t)t * KP + k] = f2bf(x - bf2f(h));
  } else {
    if (t == 0) *dmax = 0u;
    if (t < 4) ecnt[t] = 0u;
    for (int i = t; i < 4096; i += 256) deg[i] = 1.f;
    for (int i = t; i < 768; i += 256) { cmax[i] = 0u; csum[i] = 0.f; }
  }
}

// ---------------- MFMA distance tiles: 2 waves x (64x128), BK=64, XOR-swizzled 32KB LDS ----------
// slot(row,c) = c ^ (row&7); addr = row*128B + slot*16B -> bank depends on slot only; every
// wave-level b128 access (write + both frag reads) hits each bank exactly 8x = optimal.
template<int PASS>
__global__ __launch_bounds__(128) void distm_kernel(
    const ush* __restrict__ Xh,
    const float* __restrict__ sq, float* __restrict__ tmin, unsigned* __restrict__ dmax,
    uint2* __restrict__ edges, unsigned* __restrict__ ecnt, float* __restrict__ deg) {
  int t = blockIdx.x;
  int bi = (int)((sqrtf(8.f * (float)t + 1.f) - 1.f) * 0.5f);
  while ((bi + 1) * (bi + 2) / 2 <= t) ++bi;
  while (bi * (bi + 1) / 2 > t) --bi;
  int bj = t - bi * (bi + 1) / 2;  // bj <= bi

  float thr = 0.f;
  if (PASS == 1) {
    thr = 0.5f * __uint_as_float(*dmax);
    if (tmin[t] >= thr) return;
  }

  __shared__ ush L[2][8192];  // 32KB: [A,B] each [128 rows][8 chunks of 8 bf16], swizzled

  const int tid = threadIdx.x;     // 0..127
  const int lane = tid & 63;
  const int w = tid >> 6;          // wave 0..1: 64-row strip
  const int fr = lane & 15;
  const int kg = lane >> 4;

  const int Ibase = bi * 128, Jbase = bj * 128;

  f32x4 acc[4][8] = {};

  for (int k0 = 0; k0 < KPAD; k0 += 64) {
#pragma unroll
    for (int q = 0; q < 8; ++q) {
      int idx = q * 128 + tid;          // 0..1023
      int row = idx >> 3, c = idx & 7;
      int so = row * 64 + ((c ^ (row & 7)) << 3);
      *(bf16x8*)&L[0][so] = *(const bf16x8*)&Xh[(size_t)(Ibase + row) * KPAD + k0 + c * 8];
      *(bf16x8*)&L[1][so] = *(const bf16x8*)&Xh[(size_t)(Jbase + row) * KPAD + k0 + c * 8];
    }
    __syncthreads();
#pragma unroll
    for (int kk = 0; kk < 2; ++kk) {
      const int cc = kk * 4 + kg;
      bf16x8 ah[4], bh[8];
#pragma unroll
      for (int f = 0; f < 4; ++f) {
        int rowA = w * 64 + f * 16 + fr;
        ah[f] = *(const bf16x8*)&L[0][rowA * 64 + ((cc ^ (rowA & 7)) << 3)];
      }
#pragma unroll
      for (int j = 0; j < 8; ++j) {
        int rowB = j * 16 + fr;
        bh[j] = *(const bf16x8*)&L[1][rowB * 64 + ((cc ^ (rowB & 7)) << 3)];
      }
#pragma unroll
      for (int i = 0; i < 4; ++i)
#pragma unroll
        for (int j = 0; j < 8; ++j)
          acc[i][j] = __builtin_amdgcn_mfma_f32_16x16x32_bf16(ah[i], bh[j], acc[i][j], 0, 0, 0);
    }
    __syncthreads();
  }

  const int Ib = Ibase + w * 64;
  const int col = fr;  // C/D: col = lane&15, row = (lane>>4)*4 + reg

  float sqj[8];
#pragma unroll
  for (int j = 0; j < 8; ++j) sqj[j] = sq[Jbase + j * 16 + col];

  if (PASS == 0) {
    float lmin = INFINITY, lmax = -INFINITY;
#pragma unroll
    for (int i = 0; i < 4; ++i)
#pragma unroll
      for (int r = 0; r < 4; ++r) {
        int gi = Ib + i * 16 + kg * 4 + r;
        float sqi = sq[gi];
#pragma unroll
        for (int j = 0; j < 8; ++j) {
          int gj = Jbase + j * 16 + col;
          if (gi > gj) {
            float Dv = sqi + sqj[j] - 2.f * acc[i][j][r];
            lmin = fminf(lmin, Dv);
            lmax = fmaxf(lmax, Dv);
          }
        }
      }
    __syncthreads();
    float* red = (float*)L;
    red[tid] = lmin;
    red[128 + tid] = lmax;
    __syncthreads();
    for (int s2 = 64; s2 > 0; s2 >>= 1) {
      if (tid < s2) {
        red[tid] = fminf(red[tid], red[tid + s2]);
        red[128 + tid] = fmaxf(red[128 + tid], red[128 + tid + s2]);
      }
      __syncthreads();
    }
    if (tid == 0) {
      tmin[t] = red[0];
      float bmax = red[128];
      if (bmax > 0.f) atomicMax(dmax, __float_as_uint(bmax));  // positive: uint order == float order
    }
  } else {
#pragma unroll
    for (int i = 0; i < 4; ++i)
#pragma unroll
      for (int r = 0; r < 4; ++r) {
        int gi = Ib + i * 16 + kg * 4 + r;
        float sqi = sq[gi];
#pragma unroll
        for (int j = 0; j < 8; ++j) {
          int gj = Jbase + j * 16 + col;
          if (gi > gj) {
            float Dv = sqi + sqj[j] - 2.f * acc[i][j][r];
            if (Dv < thr) {
              unsigned p = atomicAdd(ecnt, 1u);
              if (p < CAP) edges[p] = make_uint2((unsigned)gi, (unsigned)gj);
              atomicAdd(&deg[gi], 1.f);
            }
          }
        }
      }
  }
}

// ---------------- MFMA GEMM 128x64 tile, 2 waves x (64x64), split-bf16, BK=64 ----------------
__global__ __launch_bounds__(128) void xwm_kernel(
    const ush* __restrict__ Xh, const ush* __restrict__ Xm, int ldx,
    const ush* __restrict__ Wth, const ush* __restrict__ Wtm, int ldw,
    float* __restrict__ C, int ksteps64) {
  const int bc = blockIdx.x;   // col block 0..3
  const int bi = blockIdx.y;   // 128-row block
  __shared__ ush LA[2][8192];  // Ah, Am: 128 rows x 64, swizzled (32KB)
  __shared__ ush LB[2][4096];  // Bh, Bm: 64 rows x 64, swizzled (16KB)

  const int tid = threadIdx.x;  // 0..127
  const int lane = tid & 63;
  const int w = tid >> 6;       // wave 0..1: 64-row strip
  const int fr = lane & 15;
  const int kg = lane >> 4;

  f32x4 acc[4][4] = {};

  for (int ks = 0; ks < ksteps64; ++ks) {
    int k0 = ks * 64;
#pragma unroll
    for (int q = 0; q < 8; ++q) {
      int idx = q * 128 + tid;          // 0..1023
      int row = idx >> 3, c = idx & 7;
      int so = row * 64 + ((c ^ (row & 7)) << 3);
      size_t ga = (size_t)(bi * 128 + row) * ldx + k0 + c * 8;
      *(bf16x8*)&LA[0][so] = *(const bf16x8*)&Xh[ga];
      *(bf16x8*)&LA[1][so] = *(const bf16x8*)&Xm[ga];
    }
#pragma unroll
    for (int q = 0; q < 4; ++q) {
      int idx = q * 128 + tid;          // 0..511
      int row = idx >> 3, c = idx & 7;
      int so = row * 64 + ((c ^ (row & 7)) << 3);
      size_t gb = (size_t)(bc * 64 + row) * ldw + k0 + c * 8;
      *(bf16x8*)&LB[0][so] = *(const bf16x8*)&Wth[gb];
      *(bf16x8*)&LB[1][so] = *(const bf16x8*)&Wtm[gb];
    }
    __syncthreads();
#pragma unroll
    for (int kk = 0; kk < 2; ++kk) {
      const int cc = kk * 4 + kg;
      bf16x8 ah[4], am[4], bh[4], bm[4];
#pragma unroll
      for (int f = 0; f < 4; ++f) {
        int rowA = w * 64 + f * 16 + fr;
        int ia = rowA * 64 + ((cc ^ (rowA & 7)) << 3);
        ah[f] = *(const bf16x8*)&LA[0][ia];
        am[f] = *(const bf16x8*)&LA[1][ia];
        int rowB = f * 16 + fr;
        int ib = rowB * 64 + ((cc ^ (rowB & 7)) << 3);
        bh[f] = *(const bf16x8*)&LB[0][ib];
        bm[f] = *(const bf16x8*)&LB[1][ib];
      }
#pragma unroll
      for (int i = 0; i < 4; ++i)
#pragma unroll
        for (int j = 0; j < 4; ++j) {
          acc[i][j] = __builtin_amdgcn_mfma_f32_16x16x32_bf16(ah[i], bh[j], acc[i][j], 0, 0, 0);
          acc[i][j] = __builtin_amdgcn_mfma_f32_16x16x32_bf16(ah[i], bm[j], acc[i][j], 0, 0, 0);
          acc[i][j] = __builtin_amdgcn_mfma_f32_16x16x32_bf16(am[i], bh[j], acc[i][j], 0, 0, 0);
        }
    }
    __syncthreads();
  }
#pragma unroll
  for (int i = 0; i < 4; ++i)
#pragma unroll
    for (int r = 0; r < 4; ++r) {
      int gr = bi * 128 + w * 64 + i * 16 + kg * 4 + r;
#pragma unroll
      for (int j = 0; j < 4; ++j) {
        int gc = bc * 64 + j * 16 + fr;
        C[(size_t)gr * H + gc] = acc[i][j][r];
      }
    }
}

// ---------------- fused GCN normalize + edge-agg + bias + relu + u,v projections ----------------
__global__ void gcnfused_kernel(const float* __restrict__ xW, const float* __restrict__ deg,
                                const uint2* __restrict__ edges, const unsigned* __restrict__ ecnt,
                                const float* __restrict__ b, const float* __restrict__ Wr,
                                const float* __restrict__ Ws,
                                float* __restrict__ y, float* __restrict__ u, float* __restrict__ v) {
  int i = blockIdx.x, t = threadIdx.x;
  float di = rsqrtf(deg[i]);
  float val = di * di * xW[(size_t)i * H + t];
  unsigned c = *ecnt; if (c > CAP) c = CAP;
  __shared__ uint2 eL[256];
  for (unsigned base = 0; base < c; base += 256) {
    unsigned m = min(256u, c - base);
    __syncthreads();
    if (t < m) eL[t] = edges[base + t];
    __syncthreads();
    for (unsigned q = 0; q < m; ++q) {
      uint2 e = eL[q];
      if (e.x == (unsigned)i) val += di * rsqrtf(deg[e.y]) * xW[(size_t)e.y * H + t];
    }
  }
  val = fmaxf(val + b[t], 0.f);
  y[(size_t)i * H + t] = val;
  float uu = val * Wr[t], vv = val * Ws[t];
  for (int off = 32; off; off >>= 1) { uu += __shfl_down(uu, off); vv += __shfl_down(vv, off); }
  __shared__ float su[4], sv[4];
  if ((t & 63) == 0) { su[t >> 6] = uu; sv[t >> 6] = vv; }
  __syncthreads();
  if (t == 0) {
    u[i] = su[0] + su[1] + su[2] + su[3];
    v[i] = sv[0] + sv[1] + sv[2] + sv[3];
  }
}

// ---------------- fused score + exact top-k (3-pass radix on 32-bit score, tie-by-index)
//                  + compaction + next-deg reinit + integrated edge filter ----------------
__global__ __launch_bounds__(1024) void select_kernel(
    const uint2* __restrict__ edges, const unsigned* __restrict__ ecnt_cur,
    const float* __restrict__ u, const float* __restrict__ v, const float* __restrict__ br,
    float* __restrict__ score, int n, int k, int* __restrict__ newid,
    unsigned* __restrict__ nextcnt, float* __restrict__ deg, uint2* __restrict__ eout) {
  __shared__ float saggL[4096];      // later reused as newidL (int)
  __shared__ unsigned keyL[4096];
  __shared__ unsigned hist[2048];
  __shared__ unsigned wsum[16];
  __shared__ unsigned sh_tot, sh_dig, sh_rem, sh_ec;

  int tid = threadIdx.x;
  int lane = tid & 63, wv = tid >> 6;

  for (int i = tid; i < 4096; i += 1024) saggL[i] = 0.f;
  for (int i = tid; i < n; i += 1024) deg[i] = 1.f;   // reinit for next layer (k < n)
  __syncthreads();
  unsigned c = *ecnt_cur; if (c > CAP) c = CAP;
  for (unsigned e = tid; e < c; e += 1024) {
    uint2 ed = edges[e];
    atomicAdd(&saggL[ed.x], u[ed.y]);
  }
  __syncthreads();

  float brv = br[0];
#pragma unroll
  for (int e = 0; e < 4; ++e) {
    int i = tid * 4 + e;
    float s = -INFINITY;
    if (i < n) { s = tanhf(saggL[i] + brv + v[i]); score[i] = s; }
    keyL[i] = fsort(s);   // pads (-inf) sort strictly below all finite scores
  }
  __syncthreads();

  // 3-pass radix select for k-th largest key (digits 11,11,10 bits)
  unsigned rem = (unsigned)k, pref = 0u, pmask = 0u;
  for (int p = 0; p < 3; ++p) {
    const int sh = (p == 0) ? 21 : (p == 1) ? 10 : 0;
    const unsigned dm = (p == 2) ? 1023u : 2047u;
    hist[tid] = 0u; hist[tid + 1024] = 0u;
    __syncthreads();
#pragma unroll
    for (int e = 0; e < 4; ++e) {
      unsigned kk = keyL[tid * 4 + e];
      if ((kk & pmask) == pref) atomicAdd(&hist[(kk >> sh) & dm], 1u);
    }
    __syncthreads();
    unsigned s0 = hist[2 * tid], s1 = hist[2 * tid + 1], ts = s0 + s1, inc = ts;
    for (int off = 1; off < 64; off <<= 1) {
      unsigned o = __shfl_up((int)inc, off, 64);
      if (lane >= off) inc += o;
    }
    if (lane == 63) wsum[wv] = inc;
    __syncthreads();
    if (tid == 0) {
      unsigned a = 0;
      for (int q = 0; q < 16; ++q) { unsigned t2 = wsum[q]; wsum[q] = a; a += t2; }
      sh_tot = a;
    }
    __syncthreads();
    unsigned excl = wsum[wv] + (inc - ts);   // count in bins [0, 2*tid)
    unsigned T = sh_tot;
    unsigned target = T - rem;               // rank from bottom of the k-th largest
    if (s0 && target >= excl && target < excl + s0) { sh_dig = 2 * tid; sh_rem = rem - (T - excl - s0); }
    unsigned e1 = excl + s0;
    if (s1 && target >= e1 && target < e1 + s1) { sh_dig = 2 * tid + 1; sh_rem = rem - (T - e1 - s1); }
    __syncthreads();
    pref |= (sh_dig << sh);
    pmask |= (dm << sh);
    rem = sh_rem;
    __syncthreads();
  }
  const unsigned P = pref;   // exact key of the k-th largest; rem = #ties to keep (lowest indices)

  // flags
  int gfl[4], tfl[4]; int nt2 = 0;
#pragma unroll
  for (int e = 0; e < 4; ++e) {
    int i = tid * 4 + e;
    unsigned kk = keyL[i];
    gfl[e] = (i < n && kk > P) ? 1 : 0;
    tfl[e] = (i < n && kk == P) ? 1 : 0;
    nt2 += tfl[e];
  }
  // exclusive block scan of tie counts (index order)
  int inc2 = nt2;
  for (int off = 1; off < 64; off <<= 1) {
    int o = __shfl_up(inc2, off, 64);
    if (lane >= off) inc2 += o;
  }
  if (lane == 63) wsum[wv] = (unsigned)inc2;
  __syncthreads();
  if (tid == 0) { unsigned a = 0; for (int q = 0; q < 16; ++q) { unsigned t3 = wsum[q]; wsum[q] = a; a += t3; } }
  __syncthreads();
  int trk = (int)wsum[wv] + (inc2 - nt2);
  // selection flags
  int sfl[4]; int ns = 0;
#pragma unroll
  for (int e = 0; e < 4; ++e) {
    int sel = gfl[e] | (tfl[e] && (unsigned)trk < rem);
    trk += tfl[e];
    sfl[e] = sel; ns += sel;
  }
  __syncthreads();  // wsum reuse
  int inc3 = ns;
  for (int off = 1; off < 64; off <<= 1) {
    int o = __shfl_up(inc3, off, 64);
    if (lane >= off) inc3 += o;
  }
  if (lane == 63) wsum[wv] = (unsigned)inc3;
  __syncthreads();
  if (tid == 0) { unsigned a = 0; for (int q = 0; q < 16; ++q) { unsigned t3 = wsum[q]; wsum[q] = a; a += t3; } }
  __syncthreads();
  int slot = (int)wsum[wv] + (inc3 - ns);
  int* newidL = (int*)saggL;
#pragma unroll
  for (int e = 0; e < 4; ++e) {
    int i = tid * 4 + e;
    int id = -1;
    if (sfl[e]) id = slot++;
    if (i < n) newid[i] = id;
    newidL[i] = (i < n) ? id : -1;
  }
  if (tid == 0) sh_ec = 0u;
  __syncthreads();

  // integrated edge filter + next-layer deg accumulation
  if (eout) {
    for (unsigned e = tid; e < c; e += 1024) {
      uint2 ed = edges[e];
      int a2 = newidL[ed.x], b2 = newidL[ed.y];
      if (a2 >= 0 && b2 >= 0) {
        unsigned pp = atomicAdd(&sh_ec, 1u);
        if (pp < CAP) eout[pp] = make_uint2((unsigned)a2, (unsigned)b2);
        atomicAdd(&deg[a2], 1.f);
      }
    }
  }
  __syncthreads();
  if (tid == 0 && nextcnt) *nextcnt = (sh_ec > CAP) ? CAP : sh_ec;
}

// gather into slots (split-bf16) + per-block register readout, one atomic per block per column
__global__ void gather_kernel(const float* __restrict__ y, const int* __restrict__ newid,
                              const float* __restrict__ score,
                              ush* __restrict__ Yh, ush* __restrict__ Ym,
                              unsigned* __restrict__ cmax, float* __restrict__ csum, int n) {
  int t = threadIdx.x;
  float m = -INFINITY, s = 0.f;
  for (int i = blockIdx.x; i < n; i += gridDim.x) {
    int slot = newid[i];
    if (slot < 0) continue;
    float vv = y[(size_t)i * H + t] * score[i];
    ush hh = f2bf(vv);
    Yh[(size_t)slot * H + t] = hh;
    Ym[(size_t)slot * H + t] = f2bf(vv - bf2f(hh));
    m = fmaxf(m, vv);
    s += vv;
  }
  atomicMax(&cmax[t], fsort(m));
  atomicAdd(&csum[t], s);
}

// ---------------- final: decode 3 layers' col max/sum -> out[512] ----------------
__global__ void final_kernel(const unsigned* __restrict__ cmax, const float* __restrict__ csum,
                             float* __restrict__ out) {
  int t = threadIdx.x;
  if (t < 256) {
    out[t] = funsort(cmax[t]) + funsort(cmax[256 + t]) + funsort(cmax[512 + t]);
  } else {
    int h = t - 256;
    out[t] = csum[h] * (1.f / KP1) + csum[256 + h] * (1.f / KP2) + csum[512 + h] * (1.f / KP3);
  }
}

extern "C" void kernel_launch(void* const* d_in, const int* in_sizes, int n_in,
                              void* d_out, int out_size, void* d_ws, size_t ws_size,
                              hipStream_t stream) {
  const float* feat = (const float*)d_in[0];
  const float* W1 = (const float*)d_in[1];  const float* b1 = (const float*)d_in[2];
  const float* W2 = (const float*)d_in[3];  const float* b2 = (const float*)d_in[4];
  const float* W3 = (const float*)d_in[5];  const float* b3 = (const float*)d_in[6];
  const float* Wr1 = (const float*)d_in[7]; const float* br1 = (const float*)d_in[8]; const float* Ws1 = (const float*)d_in[9];
  const float* Wr2 = (const float*)d_in[10]; const float* br2 = (const float*)d_in[11]; const float* Ws2 = (const float*)d_in[12];
  const float* Wr3 = (const float*)d_in[13]; const float* br3 = (const float*)d_in[14]; const float* Ws3 = (const float*)d_in[15];
  float* out = (float*)d_out;

  char* w = (char*)d_ws;
  size_t o = 0;
  auto alloc = [&](size_t bytes) { size_t cur = o; o += (bytes + 255) & ~(size_t)255; return cur; };
  unsigned* dmax = (unsigned*)(w + alloc(4));
  unsigned* ecnt = (unsigned*)(w + alloc(4 * 4));
  float* sq    = (float*)(w + alloc(N0 * 4));
  float* tmin  = (float*)(w + alloc(4096 * 4));
  float* deg   = (float*)(w + alloc(N0 * 4));
  float* u     = (float*)(w + alloc(N0 * 4));
  float* v     = (float*)(w + alloc(N0 * 4));
  float* score = (float*)(w + alloc(N0 * 4));
  int* newid   = (int*)(w + alloc(N0 * 4));
  unsigned* cmax = (unsigned*)(w + alloc(3 * 256 * 4));
  float* csum  = (float*)(w + alloc(3 * 256 * 4));
  uint2* edgesA = (uint2*)(w + alloc(CAP * 8));
  uint2* edgesB = (uint2*)(w + alloc(CAP * 8));
  ush* Wth1 = (ush*)(w + alloc(256 * KPAD * 2));
  ush* Wtm1 = (ush*)(w + alloc(256 * KPAD * 2));
  ush* Wth2 = (ush*)(w + alloc(256 * 256 * 2));
  ush* Wtm2 = (ush*)(w + alloc(256 * 256 * 2));
  ush* Wth3 = (ush*)(w + alloc(256 * 256 * 2));
  ush* Wtm3 = (ush*)(w + alloc(256 * 256 * 2));
  float* xW = (float*)(w + alloc((size_t)N0 * H * 4));
  float* tmp = (float*)(w + alloc((size_t)N0 * H * 4));   // hosts Yh/Ym
  float* yA = (float*)(w + alloc((size_t)N0 * H * 4));    // hosts Xh, then per-layer y
  float* yB = (float*)(w + alloc((size_t)N0 * H * 4));    // hosts Xm

  ush* Xh = (ush*)yA;   // [4096][512] bf16 (dist + layer-1 GEMM lifetime; dead before gcnfused writes y)
  ush* Xm = (ush*)yB;
  ush* Yh = (ush*)tmp;                              // pooled split-bf16 for next GEMM
  ush* Ym = (ush*)((char*)tmp + 2097152);

  pre_kernel<<<3073, 256, 0, stream>>>(feat, W1, W2, W3, Xh, Xm, sq,
                                       Wth1, Wtm1, Wth2, Wtm2, Wth3, Wtm3,
                                       dmax, ecnt, deg, cmax, csum);
  distm_kernel<0><<<528, 128, 0, stream>>>(Xh, sq, tmin, dmax, edgesA, ecnt, deg);
  distm_kernel<1><<<528, 128, 0, stream>>>(Xh, sq, tmin, dmax, edgesA, ecnt, deg);

  // ---- layer 1
  xwm_kernel<<<dim3(4, N0 / 128), 128, 0, stream>>>(Xh, Xm, KPAD, Wth1, Wtm1, KPAD, xW, KPAD / 64);
  gcnfused_kernel<<<N0, 256, 0, stream>>>(xW, deg, edgesA, &ecnt[0], b1, Wr1, Ws1, yA, u, v);
  select_kernel<<<1, 1024, 0, stream>>>(edgesA, &ecnt[0], u, v, br1, score, N0, KP1, newid, &ecnt[1], deg, edgesB);
  gather_kernel<<<64, 256, 0, stream>>>(yA, newid, score, Yh, Ym, cmax, csum, N0);

  // ---- layer 2
  xwm_kernel<<<dim3(4, KP1 / 128), 128, 0, stream>>>(Yh, Ym, H, Wth2, Wtm2, H, xW, H / 64);
  gcnfused_kernel<<<KP1, 256, 0, stream>>>(xW, deg, edgesB, &ecnt[1], b2, Wr2, Ws2, yA, u, v);
  select_kernel<<<1, 1024, 0, stream>>>(edgesB, &ecnt[1], u, v, br2, score, KP1, KP2, newid, &ecnt[2], deg, edgesA);
  gather_kernel<<<64, 256, 0, stream>>>(yA, newid, score, Yh, Ym, cmax + 256, csum + 256, KP1);

  // ---- layer 3
  xwm_kernel<<<dim3(4, KP2 / 128), 128, 0, stream>>>(Yh, Ym, H, Wth3, Wtm3, H, xW, H / 64);
  gcnfused_kernel<<<KP2, 256, 0, stream>>>(xW, deg, edgesA, &ecnt[2], b3, Wr3, Ws3, yA, u, v);
  select_kernel<<<1, 1024, 0, stream>>>(edgesA, &ecnt[2], u, v, br3, score, KP2, KP3, newid, &ecnt[3], deg, (uint2*)nullptr);
  gather_kernel<<<64, 256, 0, stream>>>(yA, newid, score, Yh, Ym, cmax + 512, csum + 512, KP2);

  final_kernel<<<1, 512, 0, stream>>>(cmax, csum, out);
}

// Round 10
// 177.275 us; speedup vs baseline: 1.1752x; 1.1752x over previous
//
#include <hip/hip_runtime.h>
#include <math.h>

#define N0 4096
#define FDIM 500
#define H 256
#define KP1 3072
#define KP2 2304
#define KP3 1728
#define CAP 131072u
#define KPAD 512

typedef __attribute__((ext_vector_type(8))) short bf16x8;
typedef __attribute__((ext_vector_type(4))) float f32x4;
typedef unsigned short ush;

__device__ inline ush f2bf(float x) {
  unsigned u = __float_as_uint(x);
  unsigned r = (u + 0x7fffu + ((u >> 16) & 1u)) >> 16;
  return (ush)r;
}
__device__ inline float bf2f(ush h) { return __uint_as_float(((unsigned)h) << 16); }
__device__ inline unsigned fsort(float f) {
  unsigned u = __float_as_uint(f);
  return (u & 0x80000000u) ? ~u : (u | 0x80000000u);
}
__device__ inline float funsort(unsigned s) {
  return __uint_as_float((s & 0x80000000u) ? (s & 0x7fffffffu) : ~s);
}

// ---------------- fused preamble: convsq (2 rows/block, float4) | Wt conv | init ----------------
__global__ void pre_kernel(const float* __restrict__ X,
                           const float* __restrict__ W1, const float* __restrict__ W2,
                           const float* __restrict__ W3,
                           ush* __restrict__ Xh, ush* __restrict__ Xm, float* __restrict__ sq,
                           ush* Wth1, ush* Wtm1, ush* Wth2, ush* Wtm2, ush* Wth3, ush* Wtm3,
                           unsigned* dmax, unsigned* ecnt, float* deg,
                           unsigned* cmax, float* csum) {
  int blk = blockIdx.x, t = threadIdx.x;
  if (blk < 2048) {
    int half = t >> 7, tt = t & 127;
    int row = blk * 2 + half;
    float s = 0.f;
    if (tt < 125) {
      float4 x4 = ((const float4*)(X + (size_t)row * FDIM))[tt];
      int kx = tt * 4;
      float xs[4] = {x4.x, x4.y, x4.z, x4.w};
      ushort4 hh, mm;
      ush h;
      h = f2bf(xs[0]); hh.x = h; mm.x = f2bf(xs[0] - bf2f(h));
      h = f2bf(xs[1]); hh.y = h; mm.y = f2bf(xs[1] - bf2f(h));
      h = f2bf(xs[2]); hh.z = h; mm.z = f2bf(xs[2] - bf2f(h));
      h = f2bf(xs[3]); hh.w = h; mm.w = f2bf(xs[3] - bf2f(h));
      *(ushort4*)&Xh[(size_t)row * KPAD + kx] = hh;
      *(ushort4*)&Xm[(size_t)row * KPAD + kx] = mm;
      s = xs[0]*xs[0] + xs[1]*xs[1] + xs[2]*xs[2] + xs[3]*xs[3];
    } else {
      int kx = 500 + (tt - 125) * 4;
      ushort4 z = {0, 0, 0, 0};
      *(ushort4*)&Xh[(size_t)row * KPAD + kx] = z;
      *(ushort4*)&Xm[(size_t)row * KPAD + kx] = z;
    }
    for (int off = 32; off; off >>= 1) s += __shfl_down(s, off);
    __shared__ float sw[4];
    if ((t & 63) == 0) sw[t >> 6] = s;
    __syncthreads();
    if ((t & 127) == 0) sq[row] = sw[half * 2] + sw[half * 2 + 1];
  } else if (blk < 3072) {
    int b = blk - 2048;
    const float* W; ush *Ph, *Pm; int K, KP, k;
    if (b < 512)      { W = W1; Ph = Wth1; Pm = Wtm1; K = FDIM; KP = 512; k = b; }
    else if (b < 768) { W = W2; Ph = Wth2; Pm = Wtm2; K = 256;  KP = 256; k = b - 512; }
    else              { W = W3; Ph = Wth3; Pm = Wtm3; K = 256;  KP = 256; k = b - 768; }
    float x = (k < K) ? W[(size_t)k * 256 + t] : 0.f;
    ush h = f2bf(x);
    Ph[(size_t)t * KP + k] = h;
    Pm[(size_t)t * KP + k] = f2bf(x - bf2f(h));
  } else {
    if (t == 0) *dmax = 0u;
    if (t < 4) ecnt[t] = 0u;
    for (int i = t; i < 4096; i += 256) deg[i] = 1.f;
    for (int i = t; i < 768; i += 256) { cmax[i] = 0u; csum[i] = 0.f; }
  }
}

// ---------------- MFMA distance tiles: bf16-only Gram, 8 waves, XOR-swizzled 16KB LDS ----------
// (round-7 structure: best measured; + register prefetch of next K-chunk)
template<int PASS>
__global__ __launch_bounds__(512) void distm_kernel(
    const ush* __restrict__ Xh,
    const float* __restrict__ sq, float* __restrict__ tmin, unsigned* __restrict__ dmax,
    uint2* __restrict__ edges, unsigned* __restrict__ ecnt, float* __restrict__ deg) {
  int t = blockIdx.x;
  int bi = (int)((sqrtf(8.f * (float)t + 1.f) - 1.f) * 0.5f);
  while ((bi + 1) * (bi + 2) / 2 <= t) ++bi;
  while (bi * (bi + 1) / 2 > t) --bi;
  int bj = t - bi * (bi + 1) / 2;  // bj <= bi

  float thr = 0.f;
  if (PASS == 1) {
    thr = 0.5f * __uint_as_float(*dmax);
    if (tmin[t] >= thr) return;
  }

  __shared__ ush L[2][4096];  // 16KB: [A,B][row*32 + slot*8]

  const int tid = threadIdx.x;
  const int lane = tid & 63;
  const int w = tid >> 6;          // 0..7
  const int wr = w >> 1;           // 0..3 (32-row strip)
  const int wc = w & 1;            // 0..1 (64-col strip)
  const int fr = lane & 15;
  const int kg = lane >> 4;

  const int Ibase = bi * 128, Jbase = bj * 128;
  const int srow = tid >> 2, sch = tid & 3;
  const size_t gA = (size_t)(Ibase + srow) * KPAD + sch * 8;
  const size_t gB = (size_t)(Jbase + srow) * KPAD + sch * 8;
  const int so = srow * 32 + ((sch ^ ((srow >> 1) & 3)) << 3);

  f32x4 acc[2][4] = {};

  bf16x8 ra = *(const bf16x8*)&Xh[gA];
  bf16x8 rb = *(const bf16x8*)&Xh[gB];
  for (int k0 = 0; k0 < KPAD; k0 += 32) {
    *(bf16x8*)&L[0][so] = ra;
    *(bf16x8*)&L[1][so] = rb;
    __syncthreads();
    if (k0 + 32 < KPAD) {                 // issue next-chunk loads early (hide under MFMA)
      ra = *(const bf16x8*)&Xh[gA + k0 + 32];
      rb = *(const bf16x8*)&Xh[gB + k0 + 32];
    }
    bf16x8 ah[2], bh[4];
#pragma unroll
    for (int f = 0; f < 2; ++f) {
      int row = wr * 32 + f * 16 + fr;
      ah[f] = *(const bf16x8*)&L[0][row * 32 + ((kg ^ ((row >> 1) & 3)) << 3)];
    }
#pragma unroll
    for (int f = 0; f < 4; ++f) {
      int row = wc * 64 + f * 16 + fr;
      bh[f] = *(const bf16x8*)&L[1][row * 32 + ((kg ^ ((row >> 1) & 3)) << 3)];
    }
#pragma unroll
    for (int i = 0; i < 2; ++i)
#pragma unroll
      for (int j = 0; j < 4; ++j)
        acc[i][j] = __builtin_amdgcn_mfma_f32_16x16x32_bf16(ah[i], bh[j], acc[i][j], 0, 0, 0);
    __syncthreads();
  }

  const int Ib = Ibase + wr * 32, Jb = Jbase + wc * 64;
  const int col = fr, rgrp = kg;  // C/D: col = lane&15, row = (lane>>4)*4 + reg

  float sqj[4];
#pragma unroll
  for (int j = 0; j < 4; ++j) sqj[j] = sq[Jb + j * 16 + col];

  if (PASS == 0) {
    float lmin = INFINITY, lmax = -INFINITY;
#pragma unroll
    for (int i = 0; i < 2; ++i)
#pragma unroll
      for (int r = 0; r < 4; ++r) {
        int gi = Ib + i * 16 + rgrp * 4 + r;
        float sqi = sq[gi];
#pragma unroll
        for (int j = 0; j < 4; ++j) {
          int gj = Jb + j * 16 + col;
          if (gi > gj) {
            float Dv = sqi + sqj[j] - 2.f * acc[i][j][r];
            lmin = fminf(lmin, Dv);
            lmax = fmaxf(lmax, Dv);
          }
        }
      }
    __syncthreads();
    float* red = (float*)L;
    red[tid] = lmin;
    red[512 + tid] = lmax;
    __syncthreads();
    for (int s2 = 256; s2 > 0; s2 >>= 1) {
      if (tid < s2) {
        red[tid] = fminf(red[tid], red[tid + s2]);
        red[512 + tid] = fmaxf(red[512 + tid], red[512 + tid + s2]);
      }
      __syncthreads();
    }
    if (tid == 0) {
      tmin[t] = red[0];
      float bmax = red[512];
      if (bmax > 0.f) atomicMax(dmax, __float_as_uint(bmax));  // positive: uint order == float order
    }
  } else {
#pragma unroll
    for (int i = 0; i < 2; ++i)
#pragma unroll
      for (int r = 0; r < 4; ++r) {
        int gi = Ib + i * 16 + rgrp * 4 + r;
        float sqi = sq[gi];
#pragma unroll
        for (int j = 0; j < 4; ++j) {
          int gj = Jb + j * 16 + col;
          if (gi > gj) {
            float Dv = sqi + sqj[j] - 2.f * acc[i][j][r];
            if (Dv < thr) {
              unsigned p = atomicAdd(ecnt, 1u);
              if (p < CAP) edges[p] = make_uint2((unsigned)gi, (unsigned)gj);
              atomicAdd(&deg[gi], 1.f);
            }
          }
        }
      }
  }
}

// ---------------- MFMA GEMM 64x64 tile, split-bf16, BK=32, XOR-swizzled LDS (round-7) ----------
__global__ __launch_bounds__(256) void xwm_kernel(
    const ush* __restrict__ Xh, const ush* __restrict__ Xm, int ldx,
    const ush* __restrict__ Wth, const ush* __restrict__ Wtm, int ldw,
    float* __restrict__ C, int ksteps) {
  const int bc = blockIdx.x;   // col block 0..3
  const int bi = blockIdx.y;   // row block
  __shared__ ush L[4][2048];   // 16KB: [Ah,Am,Bh,Bm][row*32 + slot*8]

  const int tid = threadIdx.x;
  const int lane = tid & 63;
  const int w = tid >> 6;      // wave 0..3: 16-row strip
  const int fr = lane & 15;
  const int kg = lane >> 4;

  const int srow = tid >> 2, sch = tid & 3;
  const size_t gA = (size_t)(bi * 64 + srow) * ldx + sch * 8;
  const size_t gB = (size_t)(bc * 64 + srow) * ldw + sch * 8;
  const int so = srow * 32 + ((sch ^ ((srow >> 1) & 3)) << 3);

  f32x4 acc[4] = {};

  bf16x8 rah = *(const bf16x8*)&Xh[gA];
  bf16x8 ram = *(const bf16x8*)&Xm[gA];
  bf16x8 rbh = *(const bf16x8*)&Wth[gB];
  bf16x8 rbm = *(const bf16x8*)&Wtm[gB];
  for (int ks = 0; ks < ksteps; ++ks) {
    *(bf16x8*)&L[0][so] = rah;
    *(bf16x8*)&L[1][so] = ram;
    *(bf16x8*)&L[2][so] = rbh;
    *(bf16x8*)&L[3][so] = rbm;
    __syncthreads();
    if (ks + 1 < ksteps) {               // issue next-chunk loads early
      int k1 = (ks + 1) * 32;
      rah = *(const bf16x8*)&Xh[gA + k1];
      ram = *(const bf16x8*)&Xm[gA + k1];
      rbh = *(const bf16x8*)&Wth[gB + k1];
      rbm = *(const bf16x8*)&Wtm[gB + k1];
    }
    bf16x8 ah, am, bh[4], bm[4];
    {
      int row = w * 16 + fr;
      int idx = row * 32 + ((kg ^ ((row >> 1) & 3)) << 3);
      ah = *(const bf16x8*)&L[0][idx];
      am = *(const bf16x8*)&L[1][idx];
    }
#pragma unroll
    for (int f = 0; f < 4; ++f) {
      int row = f * 16 + fr;
      int idx = row * 32 + ((kg ^ ((row >> 1) & 3)) << 3);
      bh[f] = *(const bf16x8*)&L[2][idx];
      bm[f] = *(const bf16x8*)&L[3][idx];
    }
#pragma unroll
    for (int f = 0; f < 4; ++f) {
      acc[f] = __builtin_amdgcn_mfma_f32_16x16x32_bf16(ah, bh[f], acc[f], 0, 0, 0);
      acc[f] = __builtin_amdgcn_mfma_f32_16x16x32_bf16(ah, bm[f], acc[f], 0, 0, 0);
      acc[f] = __builtin_amdgcn_mfma_f32_16x16x32_bf16(am, bh[f], acc[f], 0, 0, 0);
    }
    __syncthreads();
  }
#pragma unroll
  for (int f = 0; f < 4; ++f)
#pragma unroll
    for (int r = 0; r < 4; ++r) {
      int gr = bi * 64 + w * 16 + kg * 4 + r;
      int gc = bc * 64 + f * 16 + fr;
      C[(size_t)gr * H + gc] = acc[f][r];
    }
}

// ---------------- fused GCN normalize + edge-agg + bias + relu + u,v projections ----------------
__global__ void gcnfused_kernel(const float* __restrict__ xW, const float* __restrict__ deg,
                                const uint2* __restrict__ edges, const unsigned* __restrict__ ecnt,
                                const float* __restrict__ b, const float* __restrict__ Wr,
                                const float* __restrict__ Ws,
                                float* __restrict__ y, float* __restrict__ u, float* __restrict__ v) {
  int i = blockIdx.x, t = threadIdx.x;
  float di = rsqrtf(deg[i]);
  float val = di * di * xW[(size_t)i * H + t];
  unsigned c = *ecnt; if (c > CAP) c = CAP;
  __shared__ uint2 eL[256];
  for (unsigned base = 0; base < c; base += 256) {
    unsigned m = min(256u, c - base);
    __syncthreads();
    if (t < m) eL[t] = edges[base + t];
    __syncthreads();
    for (unsigned q = 0; q < m; ++q) {
      uint2 e = eL[q];
      if (e.x == (unsigned)i) val += di * rsqrtf(deg[e.y]) * xW[(size_t)e.y * H + t];
    }
  }
  val = fmaxf(val + b[t], 0.f);
  y[(size_t)i * H + t] = val;
  float uu = val * Wr[t], vv = val * Ws[t];
  for (int off = 32; off; off >>= 1) { uu += __shfl_down(uu, off); vv += __shfl_down(vv, off); }
  __shared__ float su[4], sv[4];
  if ((t & 63) == 0) { su[t >> 6] = uu; sv[t >> 6] = vv; }
  __syncthreads();
  if (t == 0) {
    u[i] = su[0] + su[1] + su[2] + su[3];
    v[i] = sv[0] + sv[1] + sv[2] + sv[3];
  }
}

// ---------------- fused score + exact top-k (3-pass radix on 32-bit score, tie-by-index)
//                  + compaction + next-deg reinit + integrated edge filter ----------------
__global__ __launch_bounds__(1024) void select_kernel(
    const uint2* __restrict__ edges, const unsigned* __restrict__ ecnt_cur,
    const float* __restrict__ u, const float* __restrict__ v, const float* __restrict__ br,
    float* __restrict__ score, int n, int k, int* __restrict__ newid,
    unsigned* __restrict__ nextcnt, float* __restrict__ deg, uint2* __restrict__ eout) {
  __shared__ float saggL[4096];      // later reused as newidL (int)
  __shared__ unsigned keyL[4096];
  __shared__ unsigned hist[2048];
  __shared__ unsigned wsum[16];
  __shared__ unsigned sh_tot, sh_dig, sh_rem, sh_ec;

  int tid = threadIdx.x;
  int lane = tid & 63, wv = tid >> 6;

  for (int i = tid; i < 4096; i += 1024) saggL[i] = 0.f;
  for (int i = tid; i < n; i += 1024) deg[i] = 1.f;   // reinit for next layer (k < n)
  __syncthreads();
  unsigned c = *ecnt_cur; if (c > CAP) c = CAP;
  for (unsigned e = tid; e < c; e += 1024) {
    uint2 ed = edges[e];
    atomicAdd(&saggL[ed.x], u[ed.y]);
  }
  __syncthreads();

  float brv = br[0];
#pragma unroll
  for (int e = 0; e < 4; ++e) {
    int i = tid * 4 + e;
    float s = -INFINITY;
    if (i < n) { s = tanhf(saggL[i] + brv + v[i]); score[i] = s; }
    keyL[i] = fsort(s);   // pads (-inf) sort strictly below all finite scores
  }
  __syncthreads();

  // 3-pass radix select for k-th largest key (digits 11,11,10 bits)
  unsigned rem = (unsigned)k, pref = 0u, pmask = 0u;
  for (int p = 0; p < 3; ++p) {
    const int sh = (p == 0) ? 21 : (p == 1) ? 10 : 0;
    const unsigned dm = (p == 2) ? 1023u : 2047u;
    hist[tid] = 0u; hist[tid + 1024] = 0u;
    __syncthreads();
#pragma unroll
    for (int e = 0; e < 4; ++e) {
      unsigned kk = keyL[tid * 4 + e];
      if ((kk & pmask) == pref) atomicAdd(&hist[(kk >> sh) & dm], 1u);
    }
    __syncthreads();
    unsigned s0 = hist[2 * tid], s1 = hist[2 * tid + 1], ts = s0 + s1, inc = ts;
    for (int off = 1; off < 64; off <<= 1) {
      unsigned o = __shfl_up((int)inc, off, 64);
      if (lane >= off) inc += o;
    }
    if (lane == 63) wsum[wv] = inc;
    __syncthreads();
    if (tid == 0) {
      unsigned a = 0;
      for (int q = 0; q < 16; ++q) { unsigned t2 = wsum[q]; wsum[q] = a; a += t2; }
      sh_tot = a;
    }
    __syncthreads();
    unsigned excl = wsum[wv] + (inc - ts);   // count in bins [0, 2*tid)
    unsigned T = sh_tot;
    unsigned target = T - rem;               // rank from bottom of the k-th largest
    if (s0 && target >= excl && target < excl + s0) { sh_dig = 2 * tid; sh_rem = rem - (T - excl - s0); }
    unsigned e1 = excl + s0;
    if (s1 && target >= e1 && target < e1 + s1) { sh_dig = 2 * tid + 1; sh_rem = rem - (T - e1 - s1); }
    __syncthreads();
    pref |= (sh_dig << sh);
    pmask |= (dm << sh);
    rem = sh_rem;
    __syncthreads();
  }
  const unsigned P = pref;   // exact key of the k-th largest; rem = #ties to keep (lowest indices)

  // flags
  int gfl[4], tfl[4]; int nt2 = 0;
#pragma unroll
  for (int e = 0; e < 4; ++e) {
    int i = tid * 4 + e;
    unsigned kk = keyL[i];
    gfl[e] = (i < n && kk > P) ? 1 : 0;
    tfl[e] = (i < n && kk == P) ? 1 : 0;
    nt2 += tfl[e];
  }
  // exclusive block scan of tie counts (index order)
  int inc2 = nt2;
  for (int off = 1; off < 64; off <<= 1) {
    int o = __shfl_up(inc2, off, 64);
    if (lane >= off) inc2 += o;
  }
  if (lane == 63) wsum[wv] = (unsigned)inc2;
  __syncthreads();
  if (tid == 0) { unsigned a = 0; for (int q = 0; q < 16; ++q) { unsigned t3 = wsum[q]; wsum[q] = a; a += t3; } }
  __syncthreads();
  int trk = (int)wsum[wv] + (inc2 - nt2);
  // selection flags
  int sfl[4]; int ns = 0;
#pragma unroll
  for (int e = 0; e < 4; ++e) {
    int sel = gfl[e] | (tfl[e] && (unsigned)trk < rem);
    trk += tfl[e];
    sfl[e] = sel; ns += sel;
  }
  __syncthreads();  // wsum reuse
  int inc3 = ns;
  for (int off = 1; off < 64; off <<= 1) {
    int o = __shfl_up(inc3, off, 64);
    if (lane >= off) inc3 += o;
  }
  if (lane == 63) wsum[wv] = (unsigned)inc3;
  __syncthreads();
  if (tid == 0) { unsigned a = 0; for (int q = 0; q < 16; ++q) { unsigned t3 = wsum[q]; wsum[q] = a; a += t3; } }
  __syncthreads();
  int slot = (int)wsum[wv] + (inc3 - ns);
  int* newidL = (int*)saggL;
#pragma unroll
  for (int e = 0; e < 4; ++e) {
    int i = tid * 4 + e;
    int id = -1;
    if (sfl[e]) id = slot++;
    if (i < n) newid[i] = id;
    newidL[i] = (i < n) ? id : -1;
  }
  if (tid == 0) sh_ec = 0u;
  __syncthreads();

  // integrated edge filter + next-layer deg accumulation
  if (eout) {
    for (unsigned e = tid; e < c; e += 1024) {
      uint2 ed = edges[e];
      int a2 = newidL[ed.x], b2 = newidL[ed.y];
      if (a2 >= 0 && b2 >= 0) {
        unsigned pp = atomicAdd(&sh_ec, 1u);
        if (pp < CAP) eout[pp] = make_uint2((unsigned)a2, (unsigned)b2);
        atomicAdd(&deg[a2], 1.f);
      }
    }
  }
  __syncthreads();
  if (tid == 0 && nextcnt) *nextcnt = (sh_ec > CAP) ? CAP : sh_ec;
}

// gather into slots (split-bf16) + per-block register readout, one atomic per block per column
__global__ void gather_kernel(const float* __restrict__ y, const int* __restrict__ newid,
                              const float* __restrict__ score,
                              ush* __restrict__ Yh, ush* __restrict__ Ym,
                              unsigned* __restrict__ cmax, float* __restrict__ csum, int n) {
  int t = threadIdx.x;
  float m = -INFINITY, s = 0.f;
  for (int i = blockIdx.x; i < n; i += gridDim.x) {
    int slot = newid[i];
    if (slot < 0) continue;
    float vv = y[(size_t)i * H + t] * score[i];
    ush hh = f2bf(vv);
    Yh[(size_t)slot * H + t] = hh;
    Ym[(size_t)slot * H + t] = f2bf(vv - bf2f(hh));
    m = fmaxf(m, vv);
    s += vv;
  }
  atomicMax(&cmax[t], fsort(m));
  atomicAdd(&csum[t], s);
}

// ---------------- final: decode 3 layers' col max/sum -> out[512] ----------------
__global__ void final_kernel(const unsigned* __restrict__ cmax, const float* __restrict__ csum,
                             float* __restrict__ out) {
  int t = threadIdx.x;
  if (t < 256) {
    out[t] = funsort(cmax[t]) + funsort(cmax[256 + t]) + funsort(cmax[512 + t]);
  } else {
    int h = t - 256;
    out[t] = csum[h] * (1.f / KP1) + csum[256 + h] * (1.f / KP2) + csum[512 + h] * (1.f / KP3);
  }
}

extern "C" void kernel_launch(void* const* d_in, const int* in_sizes, int n_in,
                              void* d_out, int out_size, void* d_ws, size_t ws_size,
                              hipStream_t stream) {
  const float* feat = (const float*)d_in[0];
  const float* W1 = (const float*)d_in[1];  const float* b1 = (const float*)d_in[2];
  const float* W2 = (const float*)d_in[3];  const float* b2 = (const float*)d_in[4];
  const float* W3 = (const float*)d_in[5];  const float* b3 = (const float*)d_in[6];
  const float* Wr1 = (const float*)d_in[7]; const float* br1 = (const float*)d_in[8]; const float* Ws1 = (const float*)d_in[9];
  const float* Wr2 = (const float*)d_in[10]; const float* br2 = (const float*)d_in[11]; const float* Ws2 = (const float*)d_in[12];
  const float* Wr3 = (const float*)d_in[13]; const float* br3 = (const float*)d_in[14]; const float* Ws3 = (const float*)d_in[15];
  float* out = (float*)d_out;

  char* w = (char*)d_ws;
  size_t o = 0;
  auto alloc = [&](size_t bytes) { size_t cur = o; o += (bytes + 255) & ~(size_t)255; return cur; };
  unsigned* dmax = (unsigned*)(w + alloc(4));
  unsigned* ecnt = (unsigned*)(w + alloc(4 * 4));
  float* sq    = (float*)(w + alloc(N0 * 4));
  float* tmin  = (float*)(w + alloc(4096 * 4));
  float* deg   = (float*)(w + alloc(N0 * 4));
  float* u     = (float*)(w + alloc(N0 * 4));
  float* v     = (float*)(w + alloc(N0 * 4));
  float* score = (float*)(w + alloc(N0 * 4));
  int* newid   = (int*)(w + alloc(N0 * 4));
  unsigned* cmax = (unsigned*)(w + alloc(3 * 256 * 4));
  float* csum  = (float*)(w + alloc(3 * 256 * 4));
  uint2* edgesA = (uint2*)(w + alloc(CAP * 8));
  uint2* edgesB = (uint2*)(w + alloc(CAP * 8));
  ush* Wth1 = (ush*)(w + alloc(256 * KPAD * 2));
  ush* Wtm1 = (ush*)(w + alloc(256 * KPAD * 2));
  ush* Wth2 = (ush*)(w + alloc(256 * 256 * 2));
  ush* Wtm2 = (ush*)(w + alloc(256 * 256 * 2));
  ush* Wth3 = (ush*)(w + alloc(256 * 256 * 2));
  ush* Wtm3 = (ush*)(w + alloc(256 * 256 * 2));
  float* xW = (float*)(w + alloc((size_t)N0 * H * 4));
  float* tmp = (float*)(w + alloc((size_t)N0 * H * 4));   // hosts Yh/Ym
  float* yA = (float*)(w + alloc((size_t)N0 * H * 4));    // hosts Xh, then per-layer y
  float* yB = (float*)(w + alloc((size_t)N0 * H * 4));    // hosts Xm

  ush* Xh = (ush*)yA;   // [4096][512] bf16 (dist + layer-1 GEMM lifetime; dead before gcnfused writes y)
  ush* Xm = (ush*)yB;
  ush* Yh = (ush*)tmp;                              // pooled split-bf16 for next GEMM
  ush* Ym = (ush*)((char*)tmp + 2097152);

  pre_kernel<<<3073, 256, 0, stream>>>(feat, W1, W2, W3, Xh, Xm, sq,
                                       Wth1, Wtm1, Wth2, Wtm2, Wth3, Wtm3,
                                       dmax, ecnt, deg, cmax, csum);
  distm_kernel<0><<<528, 512, 0, stream>>>(Xh, sq, tmin, dmax, edgesA, ecnt, deg);
  distm_kernel<1><<<528, 512, 0, stream>>>(Xh, sq, tmin, dmax, edgesA, ecnt, deg);

  // ---- layer 1
  xwm_kernel<<<dim3(4, N0 / 64), 256, 0, stream>>>(Xh, Xm, KPAD, Wth1, Wtm1, KPAD, xW, KPAD / 32);
  gcnfused_kernel<<<N0, 256, 0, stream>>>(xW, deg, edgesA, &ecnt[0], b1, Wr1, Ws1, yA, u, v);
  select_kernel<<<1, 1024, 0, stream>>>(edgesA, &ecnt[0], u, v, br1, score, N0, KP1, newid, &ecnt[1], deg, edgesB);
  gather_kernel<<<64, 256, 0, stream>>>(yA, newid, score, Yh, Ym, cmax, csum, N0);

  // ---- layer 2
  xwm_kernel<<<dim3(4, KP1 / 64), 256, 0, stream>>>(Yh, Ym, H, Wth2, Wtm2, H, xW, H / 32);
  gcnfused_kernel<<<KP1, 256, 0, stream>>>(xW, deg, edgesB, &ecnt[1], b2, Wr2, Ws2, yA, u, v);
  select_kernel<<<1, 1024, 0, stream>>>(edgesB, &ecnt[1], u, v, br2, score, KP1, KP2, newid, &ecnt[2], deg, edgesA);
  gather_kernel<<<64, 256, 0, stream>>>(yA, newid, score, Yh, Ym, cmax + 256, csum + 256, KP1);

  // ---- layer 3
  xwm_kernel<<<dim3(4, KP2 / 64), 256, 0, stream>>>(Yh, Ym, H, Wth3, Wtm3, H, xW, H / 32);
  gcnfused_kernel<<<KP2, 256, 0, stream>>>(xW, deg, edgesA, &ecnt[2], b3, Wr3, Ws3, yA, u, v);
  select_kernel<<<1, 1024, 0, stream>>>(edgesA, &ecnt[2], u, v, br3, score, KP2, KP3, newid, &ecnt[3], deg, (uint2*)nullptr);
  gather_kernel<<<64, 256, 0, stream>>>(yA, newid, score, Yh, Ym, cmax + 512, csum + 512, KP2);

  final_kernel<<<1, 512, 0, stream>>>(cmax, csum, out);
}

// Round 11
// 147.657 us; speedup vs baseline: 1.4109x; 1.2006x over previous
//
#include <hip/hip_runtime.h>
#include <math.h>

#define N0 4096
#define FDIM 500
#define H 256
#define KP1 3072
#define KP2 2304
#define KP3 1728
#define CAP 131072u
#define KPAD 512

typedef __attribute__((ext_vector_type(8))) short bf16x8;
typedef __attribute__((ext_vector_type(4))) float f32x4;
typedef unsigned short ush;

__device__ inline ush f2bf(float x) {
  unsigned u = __float_as_uint(x);
  unsigned r = (u + 0x7fffu + ((u >> 16) & 1u)) >> 16;
  return (ush)r;
}
__device__ inline float bf2f(ush h) { return __uint_as_float(((unsigned)h) << 16); }
__device__ inline unsigned fsort(float f) {
  unsigned u = __float_as_uint(f);
  return (u & 0x80000000u) ? ~u : (u | 0x80000000u);
}
__device__ inline float funsort(unsigned s) {
  return __uint_as_float((s & 0x80000000u) ? (s & 0x7fffffffu) : ~s);
}

// ---------------- fused preamble: convsq (2 rows/block, float4) | Wt conv | init ----------------
__global__ void pre_kernel(const float* __restrict__ X,
                           const float* __restrict__ W1, const float* __restrict__ W2,
                           const float* __restrict__ W3,
                           ush* __restrict__ Xh, ush* __restrict__ Xm, float* __restrict__ sq,
                           ush* Wth1, ush* Wtm1, ush* Wth2, ush* Wtm2, ush* Wth3, ush* Wtm3,
                           unsigned* dmax, unsigned* ecnt, float* deg,
                           unsigned* cmax, float* csum) {
  int blk = blockIdx.x, t = threadIdx.x;
  if (blk < 2048) {
    int half = t >> 7, tt = t & 127;
    int row = blk * 2 + half;
    float s = 0.f;
    if (tt < 125) {
      float4 x4 = ((const float4*)(X + (size_t)row * FDIM))[tt];
      int kx = tt * 4;
      float xs[4] = {x4.x, x4.y, x4.z, x4.w};
      ushort4 hh, mm;
      ush h;
      h = f2bf(xs[0]); hh.x = h; mm.x = f2bf(xs[0] - bf2f(h));
      h = f2bf(xs[1]); hh.y = h; mm.y = f2bf(xs[1] - bf2f(h));
      h = f2bf(xs[2]); hh.z = h; mm.z = f2bf(xs[2] - bf2f(h));
      h = f2bf(xs[3]); hh.w = h; mm.w = f2bf(xs[3] - bf2f(h));
      *(ushort4*)&Xh[(size_t)row * KPAD + kx] = hh;
      *(ushort4*)&Xm[(size_t)row * KPAD + kx] = mm;
      s = xs[0]*xs[0] + xs[1]*xs[1] + xs[2]*xs[2] + xs[3]*xs[3];
    } else {
      int kx = 500 + (tt - 125) * 4;
      ushort4 z = {0, 0, 0, 0};
      *(ushort4*)&Xh[(size_t)row * KPAD + kx] = z;
      *(ushort4*)&Xm[(size_t)row * KPAD + kx] = z;
    }
    for (int off = 32; off; off >>= 1) s += __shfl_down(s, off);
    __shared__ float sw[4];
    if ((t & 63) == 0) sw[t >> 6] = s;
    __syncthreads();
    if ((t & 127) == 0) sq[row] = sw[half * 2] + sw[half * 2 + 1];
  } else if (blk < 3072) {
    int b = blk - 2048;
    const float* W; ush *Ph, *Pm; int K, KP, k;
    if (b < 512)      { W = W1; Ph = Wth1; Pm = Wtm1; K = FDIM; KP = 512; k = b; }
    else if (b < 768) { W = W2; Ph = Wth2; Pm = Wtm2; K = 256;  KP = 256; k = b - 512; }
    else              { W = W3; Ph = Wth3; Pm = Wtm3; K = 256;  KP = 256; k = b - 768; }
    float x = (k < K) ? W[(size_t)k * 256 + t] : 0.f;
    ush h = f2bf(x);
    Ph[(size_t)t * KP + k] = h;
    Pm[(size_t)t * KP + k] = f2bf(x - bf2f(h));
  } else {
    if (t == 0) *dmax = 0u;
    if (t < 4) ecnt[t] = 0u;
    for (int i = t; i < 4096; i += 256) deg[i] = 1.f;
    for (int i = t; i < 768; i += 256) { cmax[i] = 0u; csum[i] = 0.f; }
  }
}

// ---------------- MFMA distance tiles: bf16-only Gram, 8 waves, XOR-swizzled 16KB LDS ----------
// round-7 structure + reg prefetch + XCD-aware block swizzle (528 = 66 x 8, bijective).
template<int PASS>
__global__ __launch_bounds__(512) void distm_kernel(
    const ush* __restrict__ Xh,
    const float* __restrict__ sq, float* __restrict__ tmin, unsigned* __restrict__ dmax,
    uint2* __restrict__ edges, unsigned* __restrict__ ecnt, float* __restrict__ deg) {
  const int cpx = gridDim.x >> 3;                    // 66 chunks per XCD
  int t = (blockIdx.x & 7) * cpx + (blockIdx.x >> 3); // logical tile id, XCD-grouped
  int bi = (int)((sqrtf(8.f * (float)t + 1.f) - 1.f) * 0.5f);
  while ((bi + 1) * (bi + 2) / 2 <= t) ++bi;
  while (bi * (bi + 1) / 2 > t) --bi;
  int bj = t - bi * (bi + 1) / 2;  // bj <= bi

  float thr = 0.f;
  if (PASS == 1) {
    thr = 0.5f * __uint_as_float(*dmax);
    if (tmin[t] >= thr) return;
  }

  __shared__ ush L[2][4096];  // 16KB: [A,B][row*32 + slot*8]

  const int tid = threadIdx.x;
  const int lane = tid & 63;
  const int w = tid >> 6;          // 0..7
  const int wr = w >> 1;           // 0..3 (32-row strip)
  const int wc = w & 1;            // 0..1 (64-col strip)
  const int fr = lane & 15;
  const int kg = lane >> 4;

  const int Ibase = bi * 128, Jbase = bj * 128;
  const int srow = tid >> 2, sch = tid & 3;
  const size_t gA = (size_t)(Ibase + srow) * KPAD + sch * 8;
  const size_t gB = (size_t)(Jbase + srow) * KPAD + sch * 8;
  const int so = srow * 32 + ((sch ^ ((srow >> 1) & 3)) << 3);

  f32x4 acc[2][4] = {};

  bf16x8 ra = *(const bf16x8*)&Xh[gA];
  bf16x8 rb = *(const bf16x8*)&Xh[gB];
  for (int k0 = 0; k0 < KPAD; k0 += 32) {
    *(bf16x8*)&L[0][so] = ra;
    *(bf16x8*)&L[1][so] = rb;
    __syncthreads();
    if (k0 + 32 < KPAD) {                 // issue next-chunk loads early (hide under MFMA)
      ra = *(const bf16x8*)&Xh[gA + k0 + 32];
      rb = *(const bf16x8*)&Xh[gB + k0 + 32];
    }
    bf16x8 ah[2], bh[4];
#pragma unroll
    for (int f = 0; f < 2; ++f) {
      int row = wr * 32 + f * 16 + fr;
      ah[f] = *(const bf16x8*)&L[0][row * 32 + ((kg ^ ((row >> 1) & 3)) << 3)];
    }
#pragma unroll
    for (int f = 0; f < 4; ++f) {
      int row = wc * 64 + f * 16 + fr;
      bh[f] = *(const bf16x8*)&L[1][row * 32 + ((kg ^ ((row >> 1) & 3)) << 3)];
    }
#pragma unroll
    for (int i = 0; i < 2; ++i)
#pragma unroll
      for (int j = 0; j < 4; ++j)
        acc[i][j] = __builtin_amdgcn_mfma_f32_16x16x32_bf16(ah[i], bh[j], acc[i][j], 0, 0, 0);
    __syncthreads();
  }

  const int Ib = Ibase + wr * 32, Jb = Jbase + wc * 64;
  const int col = fr, rgrp = kg;  // C/D: col = lane&15, row = (lane>>4)*4 + reg

  float sqj[4];
#pragma unroll
  for (int j = 0; j < 4; ++j) sqj[j] = sq[Jb + j * 16 + col];

  if (PASS == 0) {
    float lmin = INFINITY, lmax = -INFINITY;
#pragma unroll
    for (int i = 0; i < 2; ++i)
#pragma unroll
      for (int r = 0; r < 4; ++r) {
        int gi = Ib + i * 16 + rgrp * 4 + r;
        float sqi = sq[gi];
#pragma unroll
        for (int j = 0; j < 4; ++j) {
          int gj = Jb + j * 16 + col;
          if (gi > gj) {
            float Dv = sqi + sqj[j] - 2.f * acc[i][j][r];
            lmin = fminf(lmin, Dv);
            lmax = fmaxf(lmax, Dv);
          }
        }
      }
    __syncthreads();
    float* red = (float*)L;
    red[tid] = lmin;
    red[512 + tid] = lmax;
    __syncthreads();
    for (int s2 = 256; s2 > 0; s2 >>= 1) {
      if (tid < s2) {
        red[tid] = fminf(red[tid], red[tid + s2]);
        red[512 + tid] = fmaxf(red[512 + tid], red[512 + tid + s2]);
      }
      __syncthreads();
    }
    if (tid == 0) {
      tmin[t] = red[0];
      float bmax = red[512];
      if (bmax > 0.f) atomicMax(dmax, __float_as_uint(bmax));  // positive: uint order == float order
    }
  } else {
#pragma unroll
    for (int i = 0; i < 2; ++i)
#pragma unroll
      for (int r = 0; r < 4; ++r) {
        int gi = Ib + i * 16 + rgrp * 4 + r;
        float sqi = sq[gi];
#pragma unroll
        for (int j = 0; j < 4; ++j) {
          int gj = Jb + j * 16 + col;
          if (gi > gj) {
            float Dv = sqi + sqj[j] - 2.f * acc[i][j][r];
            if (Dv < thr) {
              unsigned p = atomicAdd(ecnt, 1u);
              if (p < CAP) edges[p] = make_uint2((unsigned)gi, (unsigned)gj);
              atomicAdd(&deg[gi], 1.f);
            }
          }
        }
      }
  }
}

// ---------------- MFMA GEMM 64x64 tile, split-bf16, BK=32; 1D grid + XCD swizzle ----------------
__global__ __launch_bounds__(256) void xwm_kernel(
    const ush* __restrict__ Xh, const ush* __restrict__ Xm, int ldx,
    const ush* __restrict__ Wth, const ush* __restrict__ Wtm, int ldw,
    float* __restrict__ C, int ksteps) {
  const int cpx = gridDim.x >> 3;
  int swz = (blockIdx.x & 7) * cpx + (blockIdx.x >> 3);
  const int bc = swz & 3;      // col block 0..3 (consecutive swz share bi -> A-panel L2 reuse)
  const int bi = swz >> 2;     // row block
  __shared__ ush L[4][2048];   // 16KB: [Ah,Am,Bh,Bm][row*32 + slot*8]

  const int tid = threadIdx.x;
  const int lane = tid & 63;
  const int w = tid >> 6;      // wave 0..3: 16-row strip
  const int fr = lane & 15;
  const int kg = lane >> 4;

  const int srow = tid >> 2, sch = tid & 3;
  const size_t gA = (size_t)(bi * 64 + srow) * ldx + sch * 8;
  const size_t gB = (size_t)(bc * 64 + srow) * ldw + sch * 8;
  const int so = srow * 32 + ((sch ^ ((srow >> 1) & 3)) << 3);

  f32x4 acc[4] = {};

  bf16x8 rah = *(const bf16x8*)&Xh[gA];
  bf16x8 ram = *(const bf16x8*)&Xm[gA];
  bf16x8 rbh = *(const bf16x8*)&Wth[gB];
  bf16x8 rbm = *(const bf16x8*)&Wtm[gB];
  for (int ks = 0; ks < ksteps; ++ks) {
    *(bf16x8*)&L[0][so] = rah;
    *(bf16x8*)&L[1][so] = ram;
    *(bf16x8*)&L[2][so] = rbh;
    *(bf16x8*)&L[3][so] = rbm;
    __syncthreads();
    if (ks + 1 < ksteps) {               // issue next-chunk loads early
      int k1 = (ks + 1) * 32;
      rah = *(const bf16x8*)&Xh[gA + k1];
      ram = *(const bf16x8*)&Xm[gA + k1];
      rbh = *(const bf16x8*)&Wth[gB + k1];
      rbm = *(const bf16x8*)&Wtm[gB + k1];
    }
    bf16x8 ah, am, bh[4], bm[4];
    {
      int row = w * 16 + fr;
      int idx = row * 32 + ((kg ^ ((row >> 1) & 3)) << 3);
      ah = *(const bf16x8*)&L[0][idx];
      am = *(const bf16x8*)&L[1][idx];
    }
#pragma unroll
    for (int f = 0; f < 4; ++f) {
      int row = f * 16 + fr;
      int idx = row * 32 + ((kg ^ ((row >> 1) & 3)) << 3);
      bh[f] = *(const bf16x8*)&L[2][idx];
      bm[f] = *(const bf16x8*)&L[3][idx];
    }
#pragma unroll
    for (int f = 0; f < 4; ++f) {
      acc[f] = __builtin_amdgcn_mfma_f32_16x16x32_bf16(ah, bh[f], acc[f], 0, 0, 0);
      acc[f] = __builtin_amdgcn_mfma_f32_16x16x32_bf16(ah, bm[f], acc[f], 0, 0, 0);
      acc[f] = __builtin_amdgcn_mfma_f32_16x16x32_bf16(am, bh[f], acc[f], 0, 0, 0);
    }
    __syncthreads();
  }
#pragma unroll
  for (int f = 0; f < 4; ++f)
#pragma unroll
    for (int r = 0; r < 4; ++r) {
      int gr = bi * 64 + w * 16 + kg * 4 + r;
      int gc = bc * 64 + f * 16 + fr;
      C[(size_t)gr * H + gc] = acc[f][r];
    }
}

// ---------------- fused GCN normalize + edge-agg + bias + relu + u,v projections ----------------
__global__ void gcnfused_kernel(const float* __restrict__ xW, const float* __restrict__ deg,
                                const uint2* __restrict__ edges, const unsigned* __restrict__ ecnt,
                                const float* __restrict__ b, const float* __restrict__ Wr,
                                const float* __restrict__ Ws,
                                float* __restrict__ y, float* __restrict__ u, float* __restrict__ v) {
  int i = blockIdx.x, t = threadIdx.x;
  float di = rsqrtf(deg[i]);
  float val = di * di * xW[(size_t)i * H + t];
  unsigned c = *ecnt; if (c > CAP) c = CAP;
  __shared__ uint2 eL[256];
  for (unsigned base = 0; base < c; base += 256) {
    unsigned m = min(256u, c - base);
    __syncthreads();
    if (t < m) eL[t] = edges[base + t];
    __syncthreads();
    for (unsigned q = 0; q < m; ++q) {
      uint2 e = eL[q];
      if (e.x == (unsigned)i) val += di * rsqrtf(deg[e.y]) * xW[(size_t)e.y * H + t];
    }
  }
  val = fmaxf(val + b[t], 0.f);
  y[(size_t)i * H + t] = val;
  float uu = val * Wr[t], vv = val * Ws[t];
  for (int off = 32; off; off >>= 1) { uu += __shfl_down(uu, off); vv += __shfl_down(vv, off); }
  __shared__ float su[4], sv[4];
  if ((t & 63) == 0) { su[t >> 6] = uu; sv[t >> 6] = vv; }
  __syncthreads();
  if (t == 0) {
    u[i] = su[0] + su[1] + su[2] + su[3];
    v[i] = sv[0] + sv[1] + sv[2] + sv[3];
  }
}

// ---------------- fused score + exact top-k (3-pass radix on 32-bit score, tie-by-index)
//                  + compaction + next-deg reinit + integrated edge filter ----------------
__global__ __launch_bounds__(1024) void select_kernel(
    const uint2* __restrict__ edges, const unsigned* __restrict__ ecnt_cur,
    const float* __restrict__ u, const float* __restrict__ v, const float* __restrict__ br,
    float* __restrict__ score, int n, int k, int* __restrict__ newid,
    unsigned* __restrict__ nextcnt, float* __restrict__ deg, uint2* __restrict__ eout) {
  __shared__ float saggL[4096];      // later reused as newidL (int)
  __shared__ unsigned keyL[4096];
  __shared__ unsigned hist[2048];
  __shared__ unsigned wsum[16];
  __shared__ unsigned sh_tot, sh_dig, sh_rem, sh_ec;

  int tid = threadIdx.x;
  int lane = tid & 63, wv = tid >> 6;

  for (int i = tid; i < 4096; i += 1024) saggL[i] = 0.f;
  for (int i = tid; i < n; i += 1024) deg[i] = 1.f;   // reinit for next layer (k < n)
  __syncthreads();
  unsigned c = *ecnt_cur; if (c > CAP) c = CAP;
  for (unsigned e = tid; e < c; e += 1024) {
    uint2 ed = edges[e];
    atomicAdd(&saggL[ed.x], u[ed.y]);
  }
  __syncthreads();

  float brv = br[0];
#pragma unroll
  for (int e = 0; e < 4; ++e) {
    int i = tid * 4 + e;
    float s = -INFINITY;
    if (i < n) { s = tanhf(saggL[i] + brv + v[i]); score[i] = s; }
    keyL[i] = fsort(s);   // pads (-inf) sort strictly below all finite scores
  }
  __syncthreads();

  // 3-pass radix select for k-th largest key (digits 11,11,10 bits)
  unsigned rem = (unsigned)k, pref = 0u, pmask = 0u;
  for (int p = 0; p < 3; ++p) {
    const int sh = (p == 0) ? 21 : (p == 1) ? 10 : 0;
    const unsigned dm = (p == 2) ? 1023u : 2047u;
    hist[tid] = 0u; hist[tid + 1024] = 0u;
    __syncthreads();
#pragma unroll
    for (int e = 0; e < 4; ++e) {
      unsigned kk = keyL[tid * 4 + e];
      if ((kk & pmask) == pref) atomicAdd(&hist[(kk >> sh) & dm], 1u);
    }
    __syncthreads();
    unsigned s0 = hist[2 * tid], s1 = hist[2 * tid + 1], ts = s0 + s1, inc = ts;
    for (int off = 1; off < 64; off <<= 1) {
      unsigned o = __shfl_up((int)inc, off, 64);
      if (lane >= off) inc += o;
    }
    if (lane == 63) wsum[wv] = inc;
    __syncthreads();
    if (tid == 0) {
      unsigned a = 0;
      for (int q = 0; q < 16; ++q) { unsigned t2 = wsum[q]; wsum[q] = a; a += t2; }
      sh_tot = a;
    }
    __syncthreads();
    unsigned excl = wsum[wv] + (inc - ts);   // count in bins [0, 2*tid)
    unsigned T = sh_tot;
    unsigned target = T - rem;               // rank from bottom of the k-th largest
    if (s0 && target >= excl && target < excl + s0) { sh_dig = 2 * tid; sh_rem = rem - (T - excl - s0); }
    unsigned e1 = excl + s0;
    if (s1 && target >= e1 && target < e1 + s1) { sh_dig = 2 * tid + 1; sh_rem = rem - (T - e1 - s1); }
    __syncthreads();
    pref |= (sh_dig << sh);
    pmask |= (dm << sh);
    rem = sh_rem;
    __syncthreads();
  }
  const unsigned P = pref;   // exact key of the k-th largest; rem = #ties to keep (lowest indices)

  // flags
  int gfl[4], tfl[4]; int nt2 = 0;
#pragma unroll
  for (int e = 0; e < 4; ++e) {
    int i = tid * 4 + e;
    unsigned kk = keyL[i];
    gfl[e] = (i < n && kk > P) ? 1 : 0;
    tfl[e] = (i < n && kk == P) ? 1 : 0;
    nt2 += tfl[e];
  }
  // exclusive block scan of tie counts (index order)
  int inc2 = nt2;
  for (int off = 1; off < 64; off <<= 1) {
    int o = __shfl_up(inc2, off, 64);
    if (lane >= off) inc2 += o;
  }
  if (lane == 63) wsum[wv] = (unsigned)inc2;
  __syncthreads();
  if (tid == 0) { unsigned a = 0; for (int q = 0; q < 16; ++q) { unsigned t3 = wsum[q]; wsum[q] = a; a += t3; } }
  __syncthreads();
  int trk = (int)wsum[wv] + (inc2 - nt2);
  // selection flags
  int sfl[4]; int ns = 0;
#pragma unroll
  for (int e = 0; e < 4; ++e) {
    int sel = gfl[e] | (tfl[e] && (unsigned)trk < rem);
    trk += tfl[e];
    sfl[e] = sel; ns += sel;
  }
  __syncthreads();  // wsum reuse
  int inc3 = ns;
  for (int off = 1; off < 64; off <<= 1) {
    int o = __shfl_up(inc3, off, 64);
    if (lane >= off) inc3 += o;
  }
  if (lane == 63) wsum[wv] = (unsigned)inc3;
  __syncthreads();
  if (tid == 0) { unsigned a = 0; for (int q = 0; q < 16; ++q) { unsigned t3 = wsum[q]; wsum[q] = a; a += t3; } }
  __syncthreads();
  int slot = (int)wsum[wv] + (inc3 - ns);
  int* newidL = (int*)saggL;
#pragma unroll
  for (int e = 0; e < 4; ++e) {
    int i = tid * 4 + e;
    int id = -1;
    if (sfl[e]) id = slot++;
    if (i < n) newid[i] = id;
    newidL[i] = (i < n) ? id : -1;
  }
  if (tid == 0) sh_ec = 0u;
  __syncthreads();

  // integrated edge filter + next-layer deg accumulation
  if (eout) {
    for (unsigned e = tid; e < c; e += 1024) {
      uint2 ed = edges[e];
      int a2 = newidL[ed.x], b2 = newidL[ed.y];
      if (a2 >= 0 && b2 >= 0) {
        unsigned pp = atomicAdd(&sh_ec, 1u);
        if (pp < CAP) eout[pp] = make_uint2((unsigned)a2, (unsigned)b2);
        atomicAdd(&deg[a2], 1.f);
      }
    }
  }
  __syncthreads();
  if (tid == 0 && nextcnt) *nextcnt = (sh_ec > CAP) ? CAP : sh_ec;
}

// gather into slots (split-bf16) + per-block register readout, one atomic per block per column
__global__ void gather_kernel(const float* __restrict__ y, const int* __restrict__ newid,
                              const float* __restrict__ score,
                              ush* __restrict__ Yh, ush* __restrict__ Ym,
                              unsigned* __restrict__ cmax, float* __restrict__ csum, int n) {
  int t = threadIdx.x;
  float m = -INFINITY, s = 0.f;
  for (int i = blockIdx.x; i < n; i += gridDim.x) {
    int slot = newid[i];
    if (slot < 0) continue;
    float vv = y[(size_t)i * H + t] * score[i];
    ush hh = f2bf(vv);
    Yh[(size_t)slot * H + t] = hh;
    Ym[(size_t)slot * H + t] = f2bf(vv - bf2f(hh));
    m = fmaxf(m, vv);
    s += vv;
  }
  atomicMax(&cmax[t], fsort(m));
  atomicAdd(&csum[t], s);
}

// ---------------- final: decode 3 layers' col max/sum -> out[512] ----------------
__global__ void final_kernel(const unsigned* __restrict__ cmax, const float* __restrict__ csum,
                             float* __restrict__ out) {
  int t = threadIdx.x;
  if (t < 256) {
    out[t] = funsort(cmax[t]) + funsort(cmax[256 + t]) + funsort(cmax[512 + t]);
  } else {
    int h = t - 256;
    out[t] = csum[h] * (1.f / KP1) + csum[256 + h] * (1.f / KP2) + csum[512 + h] * (1.f / KP3);
  }
}

extern "C" void kernel_launch(void* const* d_in, const int* in_sizes, int n_in,
                              void* d_out, int out_size, void* d_ws, size_t ws_size,
                              hipStream_t stream) {
  const float* feat = (const float*)d_in[0];
  const float* W1 = (const float*)d_in[1];  const float* b1 = (const float*)d_in[2];
  const float* W2 = (const float*)d_in[3];  const float* b2 = (const float*)d_in[4];
  const float* W3 = (const float*)d_in[5];  const float* b3 = (const float*)d_in[6];
  const float* Wr1 = (const float*)d_in[7]; const float* br1 = (const float*)d_in[8]; const float* Ws1 = (const float*)d_in[9];
  const float* Wr2 = (const float*)d_in[10]; const float* br2 = (const float*)d_in[11]; const float* Ws2 = (const float*)d_in[12];
  const float* Wr3 = (const float*)d_in[13]; const float* br3 = (const float*)d_in[14]; const float* Ws3 = (const float*)d_in[15];
  float* out = (float*)d_out;

  char* w = (char*)d_ws;
  size_t o = 0;
  auto alloc = [&](size_t bytes) { size_t cur = o; o += (bytes + 255) & ~(size_t)255; return cur; };
  unsigned* dmax = (unsigned*)(w + alloc(4));
  unsigned* ecnt = (unsigned*)(w + alloc(4 * 4));
  float* sq    = (float*)(w + alloc(N0 * 4));
  float* tmin  = (float*)(w + alloc(4096 * 4));
  float* deg   = (float*)(w + alloc(N0 * 4));
  float* u     = (float*)(w + alloc(N0 * 4));
  float* v     = (float*)(w + alloc(N0 * 4));
  float* score = (float*)(w + alloc(N0 * 4));
  int* newid   = (int*)(w + alloc(N0 * 4));
  unsigned* cmax = (unsigned*)(w + alloc(3 * 256 * 4));
  float* csum  = (float*)(w + alloc(3 * 256 * 4));
  uint2* edgesA = (uint2*)(w + alloc(CAP * 8));
  uint2* edgesB = (uint2*)(w + alloc(CAP * 8));
  ush* Wth1 = (ush*)(w + alloc(256 * KPAD * 2));
  ush* Wtm1 = (ush*)(w + alloc(256 * KPAD * 2));
  ush* Wth2 = (ush*)(w + alloc(256 * 256 * 2));
  ush* Wtm2 = (ush*)(w + alloc(256 * 256 * 2));
  ush* Wth3 = (ush*)(w + alloc(256 * 256 * 2));
  ush* Wtm3 = (ush*)(w + alloc(256 * 256 * 2));
  float* xW = (float*)(w + alloc((size_t)N0 * H * 4));
  float* tmp = (float*)(w + alloc((size_t)N0 * H * 4));   // hosts Yh/Ym
  float* yA = (float*)(w + alloc((size_t)N0 * H * 4));    // hosts Xh, then per-layer y
  float* yB = (float*)(w + alloc((size_t)N0 * H * 4));    // hosts Xm

  ush* Xh = (ush*)yA;   // [4096][512] bf16 (dist + layer-1 GEMM lifetime; dead before gcnfused writes y)
  ush* Xm = (ush*)yB;
  ush* Yh = (ush*)tmp;                              // pooled split-bf16 for next GEMM
  ush* Ym = (ush*)((char*)tmp + 2097152);

  pre_kernel<<<3073, 256, 0, stream>>>(feat, W1, W2, W3, Xh, Xm, sq,
                                       Wth1, Wtm1, Wth2, Wtm2, Wth3, Wtm3,
                                       dmax, ecnt, deg, cmax, csum);
  distm_kernel<0><<<528, 512, 0, stream>>>(Xh, sq, tmin, dmax, edgesA, ecnt, deg);
  distm_kernel<1><<<528, 512, 0, stream>>>(Xh, sq, tmin, dmax, edgesA, ecnt, deg);

  // ---- layer 1
  xwm_kernel<<<4 * (N0 / 64), 256, 0, stream>>>(Xh, Xm, KPAD, Wth1, Wtm1, KPAD, xW, KPAD / 32);
  gcnfused_kernel<<<N0, 256, 0, stream>>>(xW, deg, edgesA, &ecnt[0], b1, Wr1, Ws1, yA, u, v);
  select_kernel<<<1, 1024, 0, stream>>>(edgesA, &ecnt[0], u, v, br1, score, N0, KP1, newid, &ecnt[1], deg, edgesB);
  gather_kernel<<<128, 256, 0, stream>>>(yA, newid, score, Yh, Ym, cmax, csum, N0);

  // ---- layer 2
  xwm_kernel<<<4 * (KP1 / 64), 256, 0, stream>>>(Yh, Ym, H, Wth2, Wtm2, H, xW, H / 32);
  gcnfused_kernel<<<KP1, 256, 0, stream>>>(xW, deg, edgesB, &ecnt[1], b2, Wr2, Ws2, yA, u, v);
  select_kernel<<<1, 1024, 0, stream>>>(edgesB, &ecnt[1], u, v, br2, score, KP1, KP2, newid, &ecnt[2], deg, edgesA);
  gather_kernel<<<128, 256, 0, stream>>>(yA, newid, score, Yh, Ym, cmax + 256, csum + 256, KP1);

  // ---- layer 3
  xwm_kernel<<<4 * (KP2 / 64), 256, 0, stream>>>(Yh, Ym, H, Wth3, Wtm3, H, xW, H / 32);
  gcnfused_kernel<<<KP2, 256, 0, stream>>>(xW, deg, edgesA, &ecnt[2], b3, Wr3, Ws3, yA, u, v);
  select_kernel<<<1, 1024, 0, stream>>>(edgesA, &ecnt[2], u, v, br3, score, KP2, KP3, newid, &ecnt[3], deg, (uint2*)nullptr);
  gather_kernel<<<128, 256, 0, stream>>>(yA, newid, score, Yh, Ym, cmax + 512, csum + 512, KP2);

  final_kernel<<<1, 512, 0, stream>>>(cmax, csum, out);
}

// Round 12
// 145.602 us; speedup vs baseline: 1.4308x; 1.0141x over previous
//
#include <hip/hip_runtime.h>
#include <math.h>

#define N0 4096
#define FDIM 500
#define H 256
#define KP1 3072
#define KP2 2304
#define KP3 1728
#define CAP 131072u
#define KPAD 512

typedef __attribute__((ext_vector_type(8))) short bf16x8;
typedef __attribute__((ext_vector_type(4))) float f32x4;
typedef unsigned short ush;

__device__ inline ush f2bf(float x) {
  unsigned u = __float_as_uint(x);
  unsigned r = (u + 0x7fffu + ((u >> 16) & 1u)) >> 16;
  return (ush)r;
}
__device__ inline float bf2f(ush h) { return __uint_as_float(((unsigned)h) << 16); }
__device__ inline unsigned fsort(float f) {
  unsigned u = __float_as_uint(f);
  return (u & 0x80000000u) ? ~u : (u | 0x80000000u);
}
__device__ inline float funsort(unsigned s) {
  return __uint_as_float((s & 0x80000000u) ? (s & 0x7fffffffu) : ~s);
}

// ---------------- fused preamble: convsq (2 rows/block, float4) | Wt conv | init ----------------
__global__ void pre_kernel(const float* __restrict__ X,
                           const float* __restrict__ W1, const float* __restrict__ W2,
                           const float* __restrict__ W3,
                           ush* __restrict__ Xh, ush* __restrict__ Xm, float* __restrict__ sq,
                           ush* Wth1, ush* Wtm1, ush* Wth2, ush* Wtm2, ush* Wth3, ush* Wtm3,
                           unsigned* dmax, unsigned* ecnt, float* deg,
                           unsigned* cmax, float* csum) {
  int blk = blockIdx.x, t = threadIdx.x;
  if (blk < 2048) {
    int half = t >> 7, tt = t & 127;
    int row = blk * 2 + half;
    float s = 0.f;
    if (tt < 125) {
      float4 x4 = ((const float4*)(X + (size_t)row * FDIM))[tt];
      int kx = tt * 4;
      float xs[4] = {x4.x, x4.y, x4.z, x4.w};
      ushort4 hh, mm;
      ush h;
      h = f2bf(xs[0]); hh.x = h; mm.x = f2bf(xs[0] - bf2f(h));
      h = f2bf(xs[1]); hh.y = h; mm.y = f2bf(xs[1] - bf2f(h));
      h = f2bf(xs[2]); hh.z = h; mm.z = f2bf(xs[2] - bf2f(h));
      h = f2bf(xs[3]); hh.w = h; mm.w = f2bf(xs[3] - bf2f(h));
      *(ushort4*)&Xh[(size_t)row * KPAD + kx] = hh;
      *(ushort4*)&Xm[(size_t)row * KPAD + kx] = mm;
      s = xs[0]*xs[0] + xs[1]*xs[1] + xs[2]*xs[2] + xs[3]*xs[3];
    } else {
      int kx = 500 + (tt - 125) * 4;
      ushort4 z = {0, 0, 0, 0};
      *(ushort4*)&Xh[(size_t)row * KPAD + kx] = z;
      *(ushort4*)&Xm[(size_t)row * KPAD + kx] = z;
    }
    for (int off = 32; off; off >>= 1) s += __shfl_down(s, off);
    __shared__ float sw[4];
    if ((t & 63) == 0) sw[t >> 6] = s;
    __syncthreads();
    if ((t & 127) == 0) sq[row] = sw[half * 2] + sw[half * 2 + 1];
  } else if (blk < 3072) {
    int b = blk - 2048;
    const float* W; ush *Ph, *Pm; int K, KP, k;
    if (b < 512)      { W = W1; Ph = Wth1; Pm = Wtm1; K = FDIM; KP = 512; k = b; }
    else if (b < 768) { W = W2; Ph = Wth2; Pm = Wtm2; K = 256;  KP = 256; k = b - 512; }
    else              { W = W3; Ph = Wth3; Pm = Wtm3; K = 256;  KP = 256; k = b - 768; }
    float x = (k < K) ? W[(size_t)k * 256 + t] : 0.f;
    ush h = f2bf(x);
    Ph[(size_t)t * KP + k] = h;
    Pm[(size_t)t * KP + k] = f2bf(x - bf2f(h));
  } else {
    if (t == 0) *dmax = 0u;
    if (t < 4) ecnt[t] = 0u;
    for (int i = t; i < 4096; i += 256) deg[i] = 1.f;
    for (int i = t; i < 768; i += 256) { cmax[i] = 0u; csum[i] = 0.f; }
  }
}

// ---------------- MFMA distance tiles: bf16 Gram, 8 waves, BK=64, XOR-swizzled 32KB LDS --------
// slot(row,c) = c ^ (row&7), 8 chunks/row: write = 8 rows x 8 slots per wave, read = 16 rows with
// slot = cc^(row&7) -> every wave b128 access hits each bank exactly 8x (optimal). XCD swizzle kept.
template<int PASS>
__global__ __launch_bounds__(512) void distm_kernel(
    const ush* __restrict__ Xh,
    const float* __restrict__ sq, float* __restrict__ tmin, unsigned* __restrict__ dmax,
    uint2* __restrict__ edges, unsigned* __restrict__ ecnt, float* __restrict__ deg) {
  const int cpx = gridDim.x >> 3;                    // 66 chunks per XCD
  int t = (blockIdx.x & 7) * cpx + (blockIdx.x >> 3); // logical tile id, XCD-grouped
  int bi = (int)((sqrtf(8.f * (float)t + 1.f) - 1.f) * 0.5f);
  while ((bi + 1) * (bi + 2) / 2 <= t) ++bi;
  while (bi * (bi + 1) / 2 > t) --bi;
  int bj = t - bi * (bi + 1) / 2;  // bj <= bi

  float thr = 0.f;
  if (PASS == 1) {
    thr = 0.5f * __uint_as_float(*dmax);
    if (tmin[t] >= thr) return;
  }

  __shared__ ush L[2][8192];  // 32KB: [A,B][row*64 + slot*8], 128 rows x 8 chunks

  const int tid = threadIdx.x;
  const int lane = tid & 63;
  const int w = tid >> 6;          // 0..7
  const int wr = w >> 1;           // 0..3 (32-row strip)
  const int wc = w & 1;            // 0..1 (64-col strip)
  const int fr = lane & 15;
  const int kg = lane >> 4;

  const int Ibase = bi * 128, Jbase = bj * 128;

  f32x4 acc[2][4] = {};

  bf16x8 ra[2], rb[2];
#pragma unroll
  for (int q = 0; q < 2; ++q) {
    int idx = q * 512 + tid;
    int row = idx >> 3, c = idx & 7;
    ra[q] = *(const bf16x8*)&Xh[(size_t)(Ibase + row) * KPAD + c * 8];
    rb[q] = *(const bf16x8*)&Xh[(size_t)(Jbase + row) * KPAD + c * 8];
  }
  for (int k0 = 0; k0 < KPAD; k0 += 64) {
#pragma unroll
    for (int q = 0; q < 2; ++q) {
      int idx = q * 512 + tid;
      int row = idx >> 3, c = idx & 7;
      int so = row * 64 + ((c ^ (row & 7)) << 3);
      *(bf16x8*)&L[0][so] = ra[q];
      *(bf16x8*)&L[1][so] = rb[q];
    }
    __syncthreads();
    if (k0 + 64 < KPAD) {                 // issue next-chunk loads early (hide under MFMA)
      int k1 = k0 + 64;
#pragma unroll
      for (int q = 0; q < 2; ++q) {
        int idx = q * 512 + tid;
        int row = idx >> 3, c = idx & 7;
        ra[q] = *(const bf16x8*)&Xh[(size_t)(Ibase + row) * KPAD + k1 + c * 8];
        rb[q] = *(const bf16x8*)&Xh[(size_t)(Jbase + row) * KPAD + k1 + c * 8];
      }
    }
#pragma unroll
    for (int half = 0; half < 2; ++half) {
      const int cc = half * 4 + kg;
      bf16x8 ah[2], bh[4];
#pragma unroll
      for (int f = 0; f < 2; ++f) {
        int row = wr * 32 + f * 16 + fr;
        ah[f] = *(const bf16x8*)&L[0][row * 64 + ((cc ^ (row & 7)) << 3)];
      }
#pragma unroll
      for (int f = 0; f < 4; ++f) {
        int row = wc * 64 + f * 16 + fr;
        bh[f] = *(const bf16x8*)&L[1][row * 64 + ((cc ^ (row & 7)) << 3)];
      }
#pragma unroll
      for (int i = 0; i < 2; ++i)
#pragma unroll
        for (int j = 0; j < 4; ++j)
          acc[i][j] = __builtin_amdgcn_mfma_f32_16x16x32_bf16(ah[i], bh[j], acc[i][j], 0, 0, 0);
    }
    __syncthreads();
  }

  const int Ib = Ibase + wr * 32, Jb = Jbase + wc * 64;
  const int col = fr, rgrp = kg;  // C/D: col = lane&15, row = (lane>>4)*4 + reg

  float sqj[4];
#pragma unroll
  for (int j = 0; j < 4; ++j) sqj[j] = sq[Jb + j * 16 + col];

  if (PASS == 0) {
    float lmin = INFINITY, lmax = -INFINITY;
#pragma unroll
    for (int i = 0; i < 2; ++i)
#pragma unroll
      for (int r = 0; r < 4; ++r) {
        int gi = Ib + i * 16 + rgrp * 4 + r;
        float sqi = sq[gi];
#pragma unroll
        for (int j = 0; j < 4; ++j) {
          int gj = Jb + j * 16 + col;
          if (gi > gj) {
            float Dv = sqi + sqj[j] - 2.f * acc[i][j][r];
            lmin = fminf(lmin, Dv);
            lmax = fmaxf(lmax, Dv);
          }
        }
      }
    __syncthreads();
    float* red = (float*)L;
    red[tid] = lmin;
    red[512 + tid] = lmax;
    __syncthreads();
    for (int s2 = 256; s2 > 0; s2 >>= 1) {
      if (tid < s2) {
        red[tid] = fminf(red[tid], red[tid + s2]);
        red[512 + tid] = fmaxf(red[512 + tid], red[512 + tid + s2]);
      }
      __syncthreads();
    }
    if (tid == 0) {
      tmin[t] = red[0];
      float bmax = red[512];
      if (bmax > 0.f) atomicMax(dmax, __float_as_uint(bmax));  // positive: uint order == float order
    }
  } else {
#pragma unroll
    for (int i = 0; i < 2; ++i)
#pragma unroll
      for (int r = 0; r < 4; ++r) {
        int gi = Ib + i * 16 + rgrp * 4 + r;
        float sqi = sq[gi];
#pragma unroll
        for (int j = 0; j < 4; ++j) {
          int gj = Jb + j * 16 + col;
          if (gi > gj) {
            float Dv = sqi + sqj[j] - 2.f * acc[i][j][r];
            if (Dv < thr) {
              unsigned p = atomicAdd(ecnt, 1u);
              if (p < CAP) edges[p] = make_uint2((unsigned)gi, (unsigned)gj);
              atomicAdd(&deg[gi], 1.f);
            }
          }
        }
      }
  }
}

// ---------------- MFMA GEMM 64x64 tile, split-bf16, BK=32; 1D grid + XCD swizzle ----------------
__global__ __launch_bounds__(256) void xwm_kernel(
    const ush* __restrict__ Xh, const ush* __restrict__ Xm, int ldx,
    const ush* __restrict__ Wth, const ush* __restrict__ Wtm, int ldw,
    float* __restrict__ C, int ksteps) {
  const int cpx = gridDim.x >> 3;
  int swz = (blockIdx.x & 7) * cpx + (blockIdx.x >> 3);
  const int bc = swz & 3;      // col block 0..3 (consecutive swz share bi -> A-panel L2 reuse)
  const int bi = swz >> 2;     // row block
  __shared__ ush L[4][2048];   // 16KB: [Ah,Am,Bh,Bm][row*32 + slot*8]

  const int tid = threadIdx.x;
  const int lane = tid & 63;
  const int w = tid >> 6;      // wave 0..3: 16-row strip
  const int fr = lane & 15;
  const int kg = lane >> 4;

  const int srow = tid >> 2, sch = tid & 3;
  const size_t gA = (size_t)(bi * 64 + srow) * ldx + sch * 8;
  const size_t gB = (size_t)(bc * 64 + srow) * ldw + sch * 8;
  const int so = srow * 32 + ((sch ^ ((srow >> 1) & 3)) << 3);

  f32x4 acc[4] = {};

  bf16x8 rah = *(const bf16x8*)&Xh[gA];
  bf16x8 ram = *(const bf16x8*)&Xm[gA];
  bf16x8 rbh = *(const bf16x8*)&Wth[gB];
  bf16x8 rbm = *(const bf16x8*)&Wtm[gB];
  for (int ks = 0; ks < ksteps; ++ks) {
    *(bf16x8*)&L[0][so] = rah;
    *(bf16x8*)&L[1][so] = ram;
    *(bf16x8*)&L[2][so] = rbh;
    *(bf16x8*)&L[3][so] = rbm;
    __syncthreads();
    if (ks + 1 < ksteps) {               // issue next-chunk loads early
      int k1 = (ks + 1) * 32;
      rah = *(const bf16x8*)&Xh[gA + k1];
      ram = *(const bf16x8*)&Xm[gA + k1];
      rbh = *(const bf16x8*)&Wth[gB + k1];
      rbm = *(const bf16x8*)&Wtm[gB + k1];
    }
    bf16x8 ah, am, bh[4], bm[4];
    {
      int row = w * 16 + fr;
      int idx = row * 32 + ((kg ^ ((row >> 1) & 3)) << 3);
      ah = *(const bf16x8*)&L[0][idx];
      am = *(const bf16x8*)&L[1][idx];
    }
#pragma unroll
    for (int f = 0; f < 4; ++f) {
      int row = f * 16 + fr;
      int idx = row * 32 + ((kg ^ ((row >> 1) & 3)) << 3);
      bh[f] = *(const bf16x8*)&L[2][idx];
      bm[f] = *(const bf16x8*)&L[3][idx];
    }
#pragma unroll
    for (int f = 0; f < 4; ++f) {
      acc[f] = __builtin_amdgcn_mfma_f32_16x16x32_bf16(ah, bh[f], acc[f], 0, 0, 0);
      acc[f] = __builtin_amdgcn_mfma_f32_16x16x32_bf16(ah, bm[f], acc[f], 0, 0, 0);
      acc[f] = __builtin_amdgcn_mfma_f32_16x16x32_bf16(am, bh[f], acc[f], 0, 0, 0);
    }
    __syncthreads();
  }
#pragma unroll
  for (int f = 0; f < 4; ++f)
#pragma unroll
    for (int r = 0; r < 4; ++r) {
      int gr = bi * 64 + w * 16 + kg * 4 + r;
      int gc = bc * 64 + f * 16 + fr;
      C[(size_t)gr * H + gc] = acc[f][r];
    }
}

// ---------------- fused GCN normalize + edge-agg + bias + relu + u,v projections ----------------
__global__ void gcnfused_kernel(const float* __restrict__ xW, const float* __restrict__ deg,
                                const uint2* __restrict__ edges, const unsigned* __restrict__ ecnt,
                                const float* __restrict__ b, const float* __restrict__ Wr,
                                const float* __restrict__ Ws,
                                float* __restrict__ y, float* __restrict__ u, float* __restrict__ v) {
  int i = blockIdx.x, t = threadIdx.x;
  float di = rsqrtf(deg[i]);
  float val = di * di * xW[(size_t)i * H + t];
  unsigned c = *ecnt; if (c > CAP) c = CAP;
  __shared__ uint2 eL[256];
  for (unsigned base = 0; base < c; base += 256) {
    unsigned m = min(256u, c - base);
    __syncthreads();
    if (t < m) eL[t] = edges[base + t];
    __syncthreads();
    for (unsigned q = 0; q < m; ++q) {
      uint2 e = eL[q];
      if (e.x == (unsigned)i) val += di * rsqrtf(deg[e.y]) * xW[(size_t)e.y * H + t];
    }
  }
  val = fmaxf(val + b[t], 0.f);
  y[(size_t)i * H + t] = val;
  float uu = val * Wr[t], vv = val * Ws[t];
  for (int off = 32; off; off >>= 1) { uu += __shfl_down(uu, off); vv += __shfl_down(vv, off); }
  __shared__ float su[4], sv[4];
  if ((t & 63) == 0) { su[t >> 6] = uu; sv[t >> 6] = vv; }
  __syncthreads();
  if (t == 0) {
    u[i] = su[0] + su[1] + su[2] + su[3];
    v[i] = sv[0] + sv[1] + sv[2] + sv[3];
  }
}

// ---------------- fused score + exact top-k (3-pass radix on 32-bit score, tie-by-index)
//                  + compaction + next-deg reinit + integrated edge filter ----------------
__global__ __launch_bounds__(1024) void select_kernel(
    const uint2* __restrict__ edges, const unsigned* __restrict__ ecnt_cur,
    const float* __restrict__ u, const float* __restrict__ v, const float* __restrict__ br,
    float* __restrict__ score, int n, int k, int* __restrict__ newid,
    unsigned* __restrict__ nextcnt, float* __restrict__ deg, uint2* __restrict__ eout) {
  __shared__ float saggL[4096];      // later reused as newidL (int)
  __shared__ unsigned keyL[4096];
  __shared__ unsigned hist[2048];
  __shared__ unsigned wsum[16];
  __shared__ unsigned sh_tot, sh_dig, sh_rem, sh_ec;

  int tid = threadIdx.x;
  int lane = tid & 63, wv = tid >> 6;

  for (int i = tid; i < 4096; i += 1024) saggL[i] = 0.f;
  for (int i = tid; i < n; i += 1024) deg[i] = 1.f;   // reinit for next layer (k < n)
  __syncthreads();
  unsigned c = *ecnt_cur; if (c > CAP) c = CAP;
  for (unsigned e = tid; e < c; e += 1024) {
    uint2 ed = edges[e];
    atomicAdd(&saggL[ed.x], u[ed.y]);
  }
  __syncthreads();

  float brv = br[0];
#pragma unroll
  for (int e = 0; e < 4; ++e) {
    int i = tid * 4 + e;
    float s = -INFINITY;
    if (i < n) { s = tanhf(saggL[i] + brv + v[i]); score[i] = s; }
    keyL[i] = fsort(s);   // pads (-inf) sort strictly below all finite scores
  }
  __syncthreads();

  // 3-pass radix select for k-th largest key (digits 11,11,10 bits)
  unsigned rem = (unsigned)k, pref = 0u, pmask = 0u;
  for (int p = 0; p < 3; ++p) {
    const int sh = (p == 0) ? 21 : (p == 1) ? 10 : 0;
    const unsigned dm = (p == 2) ? 1023u : 2047u;
    hist[tid] = 0u; hist[tid + 1024] = 0u;
    __syncthreads();
#pragma unroll
    for (int e = 0; e < 4; ++e) {
      unsigned kk = keyL[tid * 4 + e];
      if ((kk & pmask) == pref) atomicAdd(&hist[(kk >> sh) & dm], 1u);
    }
    __syncthreads();
    unsigned s0 = hist[2 * tid], s1 = hist[2 * tid + 1], ts = s0 + s1, inc = ts;
    for (int off = 1; off < 64; off <<= 1) {
      unsigned o = __shfl_up((int)inc, off, 64);
      if (lane >= off) inc += o;
    }
    if (lane == 63) wsum[wv] = inc;
    __syncthreads();
    if (tid == 0) {
      unsigned a = 0;
      for (int q = 0; q < 16; ++q) { unsigned t2 = wsum[q]; wsum[q] = a; a += t2; }
      sh_tot = a;
    }
    __syncthreads();
    unsigned excl = wsum[wv] + (inc - ts);   // count in bins [0, 2*tid)
    unsigned T = sh_tot;
    unsigned target = T - rem;               // rank from bottom of the k-th largest
    if (s0 && target >= excl && target < excl + s0) { sh_dig = 2 * tid; sh_rem = rem - (T - excl - s0); }
    unsigned e1 = excl + s0;
    if (s1 && target >= e1 && target < e1 + s1) { sh_dig = 2 * tid + 1; sh_rem = rem - (T - e1 - s1); }
    __syncthreads();
    pref |= (sh_dig << sh);
    pmask |= (dm << sh);
    rem = sh_rem;
    __syncthreads();
  }
  const unsigned P = pref;   // exact key of the k-th largest; rem = #ties to keep (lowest indices)

  // flags
  int gfl[4], tfl[4]; int nt2 = 0;
#pragma unroll
  for (int e = 0; e < 4; ++e) {
    int i = tid * 4 + e;
    unsigned kk = keyL[i];
    gfl[e] = (i < n && kk > P) ? 1 : 0;
    tfl[e] = (i < n && kk == P) ? 1 : 0;
    nt2 += tfl[e];
  }
  // exclusive block scan of tie counts (index order)
  int inc2 = nt2;
  for (int off = 1; off < 64; off <<= 1) {
    int o = __shfl_up(inc2, off, 64);
    if (lane >= off) inc2 += o;
  }
  if (lane == 63) wsum[wv] = (unsigned)inc2;
  __syncthreads();
  if (tid == 0) { unsigned a = 0; for (int q = 0; q < 16; ++q) { unsigned t3 = wsum[q]; wsum[q] = a; a += t3; } }
  __syncthreads();
  int trk = (int)wsum[wv] + (inc2 - nt2);
  // selection flags
  int sfl[4]; int ns = 0;
#pragma unroll
  for (int e = 0; e < 4; ++e) {
    int sel = gfl[e] | (tfl[e] && (unsigned)trk < rem);
    trk += tfl[e];
    sfl[e] = sel; ns += sel;
  }
  __syncthreads();  // wsum reuse
  int inc3 = ns;
  for (int off = 1; off < 64; off <<= 1) {
    int o = __shfl_up(inc3, off, 64);
    if (lane >= off) inc3 += o;
  }
  if (lane == 63) wsum[wv] = (unsigned)inc3;
  __syncthreads();
  if (tid == 0) { unsigned a = 0; for (int q = 0; q < 16; ++q) { unsigned t3 = wsum[q]; wsum[q] = a; a += t3; } }
  __syncthreads();
  int slot = (int)wsum[wv] + (inc3 - ns);
  int* newidL = (int*)saggL;
#pragma unroll
  for (int e = 0; e < 4; ++e) {
    int i = tid * 4 + e;
    int id = -1;
    if (sfl[e]) id = slot++;
    if (i < n) newid[i] = id;
    newidL[i] = (i < n) ? id : -1;
  }
  if (tid == 0) sh_ec = 0u;
  __syncthreads();

  // integrated edge filter + next-layer deg accumulation
  if (eout) {
    for (unsigned e = tid; e < c; e += 1024) {
      uint2 ed = edges[e];
      int a2 = newidL[ed.x], b2 = newidL[ed.y];
      if (a2 >= 0 && b2 >= 0) {
        unsigned pp = atomicAdd(&sh_ec, 1u);
        if (pp < CAP) eout[pp] = make_uint2((unsigned)a2, (unsigned)b2);
        atomicAdd(&deg[a2], 1.f);
      }
    }
  }
  __syncthreads();
  if (tid == 0 && nextcnt) *nextcnt = (sh_ec > CAP) ? CAP : sh_ec;
}

// gather into slots (split-bf16) + per-block register readout, one atomic per block per column
__global__ void gather_kernel(const float* __restrict__ y, const int* __restrict__ newid,
                              const float* __restrict__ score,
                              ush* __restrict__ Yh, ush* __restrict__ Ym,
                              unsigned* __restrict__ cmax, float* __restrict__ csum, int n) {
  int t = threadIdx.x;
  float m = -INFINITY, s = 0.f;
  for (int i = blockIdx.x; i < n; i += gridDim.x) {
    int slot = newid[i];
    if (slot < 0) continue;
    float vv = y[(size_t)i * H + t] * score[i];
    ush hh = f2bf(vv);
    Yh[(size_t)slot * H + t] = hh;
    Ym[(size_t)slot * H + t] = f2bf(vv - bf2f(hh));
    m = fmaxf(m, vv);
    s += vv;
  }
  atomicMax(&cmax[t], fsort(m));
  atomicAdd(&csum[t], s);
}

// ---------------- final: decode 3 layers' col max/sum -> out[512] ----------------
__global__ void final_kernel(const unsigned* __restrict__ cmax, const float* __restrict__ csum,
                             float* __restrict__ out) {
  int t = threadIdx.x;
  if (t < 256) {
    out[t] = funsort(cmax[t]) + funsort(cmax[256 + t]) + funsort(cmax[512 + t]);
  } else {
    int h = t - 256;
    out[t] = csum[h] * (1.f / KP1) + csum[256 + h] * (1.f / KP2) + csum[512 + h] * (1.f / KP3);
  }
}

extern "C" void kernel_launch(void* const* d_in, const int* in_sizes, int n_in,
                              void* d_out, int out_size, void* d_ws, size_t ws_size,
                              hipStream_t stream) {
  const float* feat = (const float*)d_in[0];
  const float* W1 = (const float*)d_in[1];  const float* b1 = (const float*)d_in[2];
  const float* W2 = (const float*)d_in[3];  const float* b2 = (const float*)d_in[4];
  const float* W3 = (const float*)d_in[5];  const float* b3 = (const float*)d_in[6];
  const float* Wr1 = (const float*)d_in[7]; const float* br1 = (const float*)d_in[8]; const float* Ws1 = (const float*)d_in[9];
  const float* Wr2 = (const float*)d_in[10]; const float* br2 = (const float*)d_in[11]; const float* Ws2 = (const float*)d_in[12];
  const float* Wr3 = (const float*)d_in[13]; const float* br3 = (const float*)d_in[14]; const float* Ws3 = (const float*)d_in[15];
  float* out = (float*)d_out;

  char* w = (char*)d_ws;
  size_t o = 0;
  auto alloc = [&](size_t bytes) { size_t cur = o; o += (bytes + 255) & ~(size_t)255; return cur; };
  unsigned* dmax = (unsigned*)(w + alloc(4));
  unsigned* ecnt = (unsigned*)(w + alloc(4 * 4));
  float* sq    = (float*)(w + alloc(N0 * 4));
  float* tmin  = (float*)(w + alloc(4096 * 4));
  float* deg   = (float*)(w + alloc(N0 * 4));
  float* u     = (float*)(w + alloc(N0 * 4));
  float* v     = (float*)(w + alloc(N0 * 4));
  float* score = (float*)(w + alloc(N0 * 4));
  int* newid   = (int*)(w + alloc(N0 * 4));
  unsigned* cmax = (unsigned*)(w + alloc(3 * 256 * 4));
  float* csum  = (float*)(w + alloc(3 * 256 * 4));
  uint2* edgesA = (uint2*)(w + alloc(CAP * 8));
  uint2* edgesB = (uint2*)(w + alloc(CAP * 8));
  ush* Wth1 = (ush*)(w + alloc(256 * KPAD * 2));
  ush* Wtm1 = (ush*)(w + alloc(256 * KPAD * 2));
  ush* Wth2 = (ush*)(w + alloc(256 * 256 * 2));
  ush* Wtm2 = (ush*)(w + alloc(256 * 256 * 2));
  ush* Wth3 = (ush*)(w + alloc(256 * 256 * 2));
  ush* Wtm3 = (ush*)(w + alloc(256 * 256 * 2));
  float* xW = (float*)(w + alloc((size_t)N0 * H * 4));
  float* tmp = (float*)(w + alloc((size_t)N0 * H * 4));   // hosts Yh/Ym
  float* yA = (float*)(w + alloc((size_t)N0 * H * 4));    // hosts Xh, then per-layer y
  float* yB = (float*)(w + alloc((size_t)N0 * H * 4));    // hosts Xm

  ush* Xh = (ush*)yA;   // [4096][512] bf16 (dist + layer-1 GEMM lifetime; dead before gcnfused writes y)
  ush* Xm = (ush*)yB;
  ush* Yh = (ush*)tmp;                              // pooled split-bf16 for next GEMM
  ush* Ym = (ush*)((char*)tmp + 2097152);

  pre_kernel<<<3073, 256, 0, stream>>>(feat, W1, W2, W3, Xh, Xm, sq,
                                       Wth1, Wtm1, Wth2, Wtm2, Wth3, Wtm3,
                                       dmax, ecnt, deg, cmax, csum);
  distm_kernel<0><<<528, 512, 0, stream>>>(Xh, sq, tmin, dmax, edgesA, ecnt, deg);
  distm_kernel<1><<<528, 512, 0, stream>>>(Xh, sq, tmin, dmax, edgesA, ecnt, deg);

  // ---- layer 1
  xwm_kernel<<<4 * (N0 / 64), 256, 0, stream>>>(Xh, Xm, KPAD, Wth1, Wtm1, KPAD, xW, KPAD / 32);
  gcnfused_kernel<<<N0, 256, 0, stream>>>(xW, deg, edgesA, &ecnt[0], b1, Wr1, Ws1, yA, u, v);
  select_kernel<<<1, 1024, 0, stream>>>(edgesA, &ecnt[0], u, v, br1, score, N0, KP1, newid, &ecnt[1], deg, edgesB);
  gather_kernel<<<128, 256, 0, stream>>>(yA, newid, score, Yh, Ym, cmax, csum, N0);

  // ---- layer 2
  xwm_kernel<<<4 * (KP1 / 64), 256, 0, stream>>>(Yh, Ym, H, Wth2, Wtm2, H, xW, H / 32);
  gcnfused_kernel<<<KP1, 256, 0, stream>>>(xW, deg, edgesB, &ecnt[1], b2, Wr2, Ws2, yA, u, v);
  select_kernel<<<1, 1024, 0, stream>>>(edgesB, &ecnt[1], u, v, br2, score, KP1, KP2, newid, &ecnt[2], deg, edgesA);
  gather_kernel<<<128, 256, 0, stream>>>(yA, newid, score, Yh, Ym, cmax + 256, csum + 256, KP1);

  // ---- layer 3
  xwm_kernel<<<4 * (KP2 / 64), 256, 0, stream>>>(Yh, Ym, H, Wth3, Wtm3, H, xW, H / 32);
  gcnfused_kernel<<<KP2, 256, 0, stream>>>(xW, deg, edgesA, &ecnt[2], b3, Wr3, Ws3, yA, u, v);
  select_kernel<<<1, 1024, 0, stream>>>(edgesA, &ecnt[2], u, v, br3, score, KP2, KP3, newid, &ecnt[3], deg, (uint2*)nullptr);
  gather_kernel<<<128, 256, 0, stream>>>(yA, newid, score, Yh, Ym, cmax + 512, csum + 512, KP2);

  final_kernel<<<1, 512, 0, stream>>>(cmax, csum, out);
}